// Round 17
// baseline (965.087 us; speedup 1.0000x reference)
//
#include <hip/hip_runtime.h>
#include <math.h>

#define V_    10000
#define VP_   10112        // padded vocab = 79*128 for 2-part Y-GEMM blocks
#define NPB_  79           // 128-col partial parts
#define E_    150
#define F_    200
#define TL_   7
#define B_    2048
#define NSEG_ 3
#define EPS_  1e-5f
#define SLOPE_ 0.01f
#define NB64  (B_/64)
#define NYB   640          // 8 xcd * 10 pair-slots * 8 b-tiles (256 rows)
#define KQ_   7            // K chunks of 32 for F_=200 (padded 224)

typedef unsigned short u16;
typedef __attribute__((ext_vector_type(8))) short bf16x8;
typedef __attribute__((ext_vector_type(4))) float f32x4;

#define SB0() __builtin_amdgcn_sched_barrier(0)

__device__ __forceinline__ float leaky_f(float x){ return x >= 0.f ? x : SLOPE_*x; }
__device__ __forceinline__ u16 bf16_rne(float x){
  unsigned u = __float_as_uint(x);
  unsigned r = (u + 0x7FFFu + ((u>>16)&1u)) >> 16;
  return (u16)r;
}
__device__ __forceinline__ float bf16_to_f(u16 h){ return __uint_as_float(((unsigned)h)<<16); }

// ---------------------------------------------------------------- transpose (XwT only)
__global__ void transpose_k(const float* __restrict__ in, float* __restrict__ out,
                            int R, int C)
{
  __shared__ float tile[32][33];
  const long long bofs = (long long)blockIdx.z * R * C;
  in += bofs; out += bofs;
  const int c0 = blockIdx.x*32, r0 = blockIdx.y*32;
  const int tx = threadIdx.x, ty = threadIdx.y;  // (32,8)
  for (int i = ty; i < 32; i += 8) {
    int r = r0 + i, c = c0 + tx;
    if (r < R && c < C) tile[i][tx] = in[(long long)r*C + c];
  }
  __syncthreads();
  for (int i = ty; i < 32; i += 8) {
    int c = c0 + i, r = r0 + tx;
    if (c < C && r < R) out[(long long)c*R + r] = tile[tx][i];
  }
}

// ---------------------------------------------------------------- embedding gather
__global__ void gather_x0(const int* __restrict__ text, const float* __restrict__ emb,
                          float* __restrict__ X0)
{
  const int b = blockIdx.x*256 + threadIdx.x;
  const int l = blockIdx.y, j = blockIdx.z;
  const int s = j*TL_ + l;
  const int row = text[(long long)s*B_ + b];
  const float* er = emb + (long long)row*E_;
  float* xp = X0 + ((long long)j*E_*TL_ + l)*B_ + b;
  for (int e = 0; e < E_; ++e) xp[(long long)e*TL_*B_] = er[e];
}

// ---------------------------------------------------------------- unified weight pack (one launch)
struct PWEnt { const float* src; u16* dh; u16* dl; int kstride; int keff; int nq; };
struct PWTab { PWEnt e[14]; };

__global__ void pack_all_w(PWTab tab)
{
  const PWEnt E = tab.e[blockIdx.y];
  const int q = blockIdx.x;
  if (q >= E.nq) return;
  const int f = threadIdx.x;        // 256
  union { u16 u[32]; uint4 v[4]; } H, L;
  #pragma unroll
  for (int kk = 0; kk < 32; ++kk) {
    const int k = q*32 + kk;
    const float x = (k < E.keff && f < F_) ? E.src[(size_t)f*E.kstride + k] : 0.f;
    const u16 h = bf16_rne(x);
    H.u[kk] = h;
    L.u[kk] = bf16_rne(x - bf16_to_f(h));
  }
  uint4* dh = (uint4*)(E.dh + ((size_t)q*256 + f)*32);
  uint4* dl = (uint4*)(E.dl + ((size_t)q*256 + f)*32);
  #pragma unroll
  for (int i = 0; i < 4; ++i) { dh[i] = H.v[i]; dl[i] = L.v[i]; }
}

// ---------------------------------------------------------------- pack fp32 [z][F][B] -> frags [z][q][B][32]
__global__ void pack_x(const float* __restrict__ X, long long xZ,
                       u16* __restrict__ Oh, u16* __restrict__ Ol, long long oZ)
{
  const int q = blockIdx.y, z = blockIdx.z;
  const int b = blockIdx.x*256 + threadIdx.x;
  X  += (size_t)z*xZ;
  Oh += (size_t)z*oZ; Ol += (size_t)z*oZ;
  union { u16 u[32]; uint4 v[4]; } H, L;
  #pragma unroll
  for (int kk = 0; kk < 32; ++kk) {
    const int k = q*32 + kk;
    const float x = (k < F_) ? X[(size_t)k*B_ + b] : 0.f;
    const u16 h = bf16_rne(x);
    H.u[kk] = h;
    L.u[kk] = bf16_rne(x - bf16_to_f(h));
  }
  uint4* dh = (uint4*)(Oh + ((size_t)q*B_ + b)*32);
  uint4* dl = (uint4*)(Ol + ((size_t)q*B_ + b)*32);
  #pragma unroll
  for (int i = 0; i < 4; ++i) { dh[i] = H.v[i]; dl[i] = L.v[i]; }
}

// ---------------------------------------------------------------- fused u_steps + frag pack
__global__ void us_pack(const float* __restrict__ Uh,
                        u16* __restrict__ Oh, u16* __restrict__ Ol, long long oZ)
{
  const int q = blockIdx.y, t = blockIdx.z;
  const int b = blockIdx.x*256 + threadIdx.x;
  const int src = (t == 0) ? 6 : t;
  const float* U = Uh + (size_t)src*F_*B_;
  Oh += (size_t)t*oZ; Ol += (size_t)t*oZ;
  union { u16 u[32]; uint4 v[4]; } H, L;
  #pragma unroll
  for (int kk = 0; kk < 32; ++kk) {
    const int k = q*32 + kk;
    float x = 0.f;
    if (k < F_) {
      x = U[(size_t)k*B_ + b];
      if (t < 5) x = leaky_f(x);
    }
    const u16 h = bf16_rne(x);
    H.u[kk] = h;
    L.u[kk] = bf16_rne(x - bf16_to_f(h));
  }
  uint4* dh = (uint4*)(Oh + ((size_t)q*B_ + b)*32);
  uint4* dl = (uint4*)(Ol + ((size_t)q*B_ + b)*32);
  #pragma unroll
  for (int i = 0; i < 4; ++i) { dh[i] = H.v[i]; dl[i] = L.v[i]; }
}

// ================================================================ MFMA fragment helpers
struct MFrag { bf16x8 h1[4], l1[4], h2[4], l2[4]; };

template<bool TWO>
__device__ __forceinline__ void m_loadq(MFrag& f, int q,
    const u16* __restrict__ X1h, const u16* __restrict__ X1l,
    const u16* __restrict__ X2h, const u16* __restrict__ X2l,
    int b0, int lr, int g)
{
  #pragma unroll
  for (int nt = 0; nt < 4; ++nt) {
    const size_t o = ((size_t)q*B_ + (b0 + nt*16 + lr))*32 + g*8;
    f.h1[nt] = *(const bf16x8*)(X1h + o);
    f.l1[nt] = *(const bf16x8*)(X1l + o);
    if (TWO) {
      f.h2[nt] = *(const bf16x8*)(X2h + o);
      f.l2[nt] = *(const bf16x8*)(X2l + o);
    }
  }
}

template<bool TWO>
__device__ __forceinline__ void m_mfma_chunk(const MFrag& f, int q,
    const u16* __restrict__ W1h, const u16* __restrict__ W1l,
    const u16* __restrict__ W2h, const u16* __restrict__ W2l,
    int f0, int w, int lr, int g, f32x4 acc[4])
{
  const size_t aoff = ((size_t)q*256 + (f0 + w*16 + lr))*32 + g*8;
  {
    const bf16x8 ah = *(const bf16x8*)(W1h + aoff);
    const bf16x8 al = *(const bf16x8*)(W1l + aoff);
    #pragma unroll
    for (int nt = 0; nt < 4; ++nt) {
      acc[nt] = __builtin_amdgcn_mfma_f32_16x16x32_bf16(ah, f.h1[nt], acc[nt], 0, 0, 0);
      acc[nt] = __builtin_amdgcn_mfma_f32_16x16x32_bf16(ah, f.l1[nt], acc[nt], 0, 0, 0);
      acc[nt] = __builtin_amdgcn_mfma_f32_16x16x32_bf16(al, f.h1[nt], acc[nt], 0, 0, 0);
    }
  }
  if (TWO) {
    const bf16x8 ah = *(const bf16x8*)(W2h + aoff);
    const bf16x8 al = *(const bf16x8*)(W2l + aoff);
    #pragma unroll
    for (int nt = 0; nt < 4; ++nt) {
      acc[nt] = __builtin_amdgcn_mfma_f32_16x16x32_bf16(ah, f.h2[nt], acc[nt], 0, 0, 0);
      acc[nt] = __builtin_amdgcn_mfma_f32_16x16x32_bf16(ah, f.l2[nt], acc[nt], 0, 0, 0);
      acc[nt] = __builtin_amdgcn_mfma_f32_16x16x32_bf16(al, f.h2[nt], acc[nt], 0, 0, 0);
    }
  }
}

// ---------------------------------------------------------------- generic MFMA GEMM (pipelined)
template<bool TWO, bool LEAKY, bool OUT_F32, bool OUT_PK>
__global__ __launch_bounds__(256) void mf_gemm(
    const u16* __restrict__ W1h, const u16* __restrict__ W1l, long long wZ,
    const u16* __restrict__ X1h, const u16* __restrict__ X1l, long long xZ,
    const u16* __restrict__ W2h, const u16* __restrict__ W2l,
    const u16* __restrict__ X2h, const u16* __restrict__ X2l,
    const float* __restrict__ bias, long long bZ,
    float* __restrict__ Cf, long long cZ,
    u16* __restrict__ Oh, u16* __restrict__ Ol)
{
  const int z = blockIdx.z;
  W1h += (size_t)z*wZ; W1l += (size_t)z*wZ;
  X1h += (size_t)z*xZ; X1l += (size_t)z*xZ;
  const float* bz = bias + (size_t)z*bZ;
  if (OUT_F32) Cf += (size_t)z*cZ;

  const int f0 = blockIdx.x*64;
  const int b0 = blockIdx.y*64;
  const int tid = threadIdx.x;
  const int w = tid >> 6, l = tid & 63;
  const int lr = l & 15, g = l >> 4;

  __shared__ float T[64][65];

  f32x4 acc[4] = {};
  MFrag fA, fB;
  m_loadq<TWO>(fA, 0, X1h, X1l, X2h, X2l, b0, lr, g);
  #pragma unroll
  for (int q = 0; q < KQ_; ++q) {
    MFrag& cur = (q & 1) ? fB : fA;
    MFrag& nxt = (q & 1) ? fA : fB;
    if (q + 1 < KQ_) m_loadq<TWO>(nxt, q + 1, X1h, X1l, X2h, X2l, b0, lr, g);
    SB0();
    m_mfma_chunk<TWO>(cur, q, W1h, W1l, W2h, W2l, f0, w, lr, g, acc);
    SB0();
  }
  #pragma unroll
  for (int nt = 0; nt < 4; ++nt)
    #pragma unroll
    for (int j = 0; j < 4; ++j)
      T[w*16 + g*4 + j][nt*16 + lr] = acc[nt][j];
  __syncthreads();

  const int ty = tid >> 4, tx = tid & 15;
  #pragma unroll
  for (int i = 0; i < 4; ++i) {
    const int f = f0 + ty*4 + i;
    if (f < F_) {
      const float bb = bz[f];
      #pragma unroll
      for (int j = 0; j < 4; ++j) {
        float v = T[ty*4 + i][tx*4 + j] + bb;
        if (LEAKY) v = leaky_f(v);
        if (OUT_F32) Cf[(size_t)f*B_ + b0 + tx*4 + j] = v;
        T[ty*4 + i][tx*4 + j] = v;
      }
    } else {
      #pragma unroll
      for (int j = 0; j < 4; ++j) T[ty*4 + i][tx*4 + j] = 0.f;
    }
  }
  __syncthreads();

  if (OUT_PK) {
    const int bcol = tid & 63;
    const int kk0 = (tid >> 6)*8;
    #pragma unroll
    for (int qh = 0; qh < 2; ++qh) {
      const int q = (f0 >> 5) + qh;
      if (q >= KQ_) continue;
      union { u16 u[8]; uint4 v2[1]; } H, L;
      #pragma unroll
      for (int u = 0; u < 8; ++u) {
        const float x = T[qh*32 + kk0 + u][bcol];
        const u16 h = bf16_rne(x);
        H.u[u] = h;
        L.u[u] = bf16_rne(x - bf16_to_f(h));
      }
      const size_t off = ((size_t)q*B_ + b0 + bcol)*32 + kk0;
      *(uint4*)(Oh + off) = H.v2[0];
      *(uint4*)(Ol + off) = L.v2[0];
    }
  }
}

// ---------------------------------------------------------------- conv GEMM v3: LDS-shared frags, 3-phase pipeline
template<int KW, int LIN, int NQ, int KEFF, bool BN, bool OUT_LEAKY>
__global__ __launch_bounds__(256) void conv_gemm3(
    const u16* __restrict__ Wh, const u16* __restrict__ Wl,
    const float* __restrict__ Y, long long yZ,
    const float* __restrict__ bnS, const float* __restrict__ bnH,
    const float* __restrict__ bias, float* __restrict__ C, long long cZ, int Lout)
{
  const int z = blockIdx.y;
  Y += (size_t)z*yZ; C += (size_t)z*cZ;
  const float* bs_ = BN ? bnS + (size_t)z*F_ : nullptr;
  const float* bh_ = BN ? bnH + (size_t)z*F_ : nullptr;

  const int c0 = blockIdx.x*64;
  const int tid = threadIdx.x;
  const int w  = tid >> 6;
  const int l  = tid & 63;
  const int lr = l & 15, g = l >> 4;

  const int col_s = tid & 63;
  const int ks    = (tid >> 6)*8;
  const int cg    = c0 + col_s;
  const int ts    = cg >> 11, bcol_s = cg & 2047;

  __shared__ u16 LH[2][64][32];
  __shared__ u16 LL[2][64][32];

  f32x4 acc[4][4] = {};
  float rawA[8], rawB[8];

  {
    const int kb = ks;
    int e = kb / KW, kw = kb - e*KW;
    #pragma unroll
    for (int u = 0; u < 8; ++u) {
      rawA[u] = ((kb + u) < KEFF) ? Y[((size_t)(e*LIN + ts + kw))*B_ + bcol_s] : 0.f;
      ++kw; if (kw == KW) { kw = 0; ++e; }
    }
    union { u16 u[8]; uint4 v; } Hh, Ll;
    e = kb / KW; kw = kb - e*KW;
    #pragma unroll
    for (int u = 0; u < 8; ++u) {
      float x = rawA[u];
      if (BN && (kb + u) < KEFF) x = leaky_f(fmaf(x, bs_[e], bh_[e]));
      const u16 h = bf16_rne(x);
      Hh.u[u] = h; Ll.u[u] = bf16_rne(x - bf16_to_f(h));
      ++kw; if (kw == KW) { kw = 0; ++e; }
    }
    *(uint4*)&LH[0][col_s][ks] = Hh.v;
    *(uint4*)&LL[0][col_s][ks] = Ll.v;
  }
  __syncthreads();

  #pragma unroll
  for (int q = 0; q < NQ; ++q) {
    const int buf = q & 1;
    float (&rw)[8] = (q & 1) ? rawA : rawB;

    if (q + 1 < NQ) {
      const int kb = (q + 1)*32 + ks;
      int e = kb / KW, kw = kb - e*KW;
      #pragma unroll
      for (int u = 0; u < 8; ++u) {
        rw[u] = ((kb + u) < KEFF) ? Y[((size_t)(e*LIN + ts + kw))*B_ + bcol_s] : 0.f;
        ++kw; if (kw == KW) { kw = 0; ++e; }
      }
    }
    SB0();
    {
      bf16x8 bh4[4], bl4[4];
      #pragma unroll
      for (int nt = 0; nt < 4; ++nt) {
        bh4[nt] = *(const bf16x8*)&LH[buf][nt*16 + lr][g*8];
        bl4[nt] = *(const bf16x8*)&LL[buf][nt*16 + lr][g*8];
      }
      bf16x8 ah[4], al[4];
      #pragma unroll
      for (int mt = 0; mt < 4; ++mt) {
        const size_t woff = ((size_t)q*256 + (w*64 + mt*16 + lr))*32 + g*8;
        ah[mt] = *(const bf16x8*)(Wh + woff);
        al[mt] = *(const bf16x8*)(Wl + woff);
      }
      #pragma unroll
      for (int mt = 0; mt < 4; ++mt)
        #pragma unroll
        for (int nt = 0; nt < 4; ++nt) {
          acc[mt][nt] = __builtin_amdgcn_mfma_f32_16x16x32_bf16(ah[mt], bh4[nt], acc[mt][nt], 0, 0, 0);
          acc[mt][nt] = __builtin_amdgcn_mfma_f32_16x16x32_bf16(ah[mt], bl4[nt], acc[mt][nt], 0, 0, 0);
          acc[mt][nt] = __builtin_amdgcn_mfma_f32_16x16x32_bf16(al[mt], bh4[nt], acc[mt][nt], 0, 0, 0);
        }
    }
    SB0();
    if (q + 1 < NQ) {
      const int kb = (q + 1)*32 + ks;
      int e = kb / KW, kw = kb - e*KW;
      union { u16 u[8]; uint4 v; } Hh, Ll;
      #pragma unroll
      for (int u = 0; u < 8; ++u) {
        float x = rw[u];
        if (BN && (kb + u) < KEFF) x = leaky_f(fmaf(x, bs_[e], bh_[e]));
        const u16 h = bf16_rne(x);
        Hh.u[u] = h; Ll.u[u] = bf16_rne(x - bf16_to_f(h));
        ++kw; if (kw == KW) { kw = 0; ++e; }
      }
      *(uint4*)&LH[buf ^ 1][col_s][ks] = Hh.v;
      *(uint4*)&LL[buf ^ 1][col_s][ks] = Ll.v;
    }
    __syncthreads();
  }

  #pragma unroll
  for (int mt = 0; mt < 4; ++mt)
    #pragma unroll
    for (int j = 0; j < 4; ++j) {
      const int f = w*64 + mt*16 + g*4 + j;
      if (f < F_) {
        const float bs = bias[f];
        #pragma unroll
        for (int nt = 0; nt < 4; ++nt) {
          const int col = c0 + nt*16 + lr;
          const int t = col >> 11, b = col & 2047;
          float v = acc[mt][nt][j] + bs;
          if (OUT_LEAKY) v = leaky_f(v);
          C[((size_t)f*Lout + t)*B_ + b] = v;
        }
      }
    }
}

// ---------------------------------------------------------------- BN stats
__global__ void bn_stats(const float* __restrict__ Y, int L,
                         const float* __restrict__ gamma, const float* __restrict__ beta,
                         float* __restrict__ scale, float* __restrict__ shift)
{
  const int f = blockIdx.x, j = blockIdx.y;
  const float* p = Y + ((long long)(j*F_ + f))*L*B_;
  const int N = L*B_;
  double s = 0.0, s2 = 0.0;
  for (int i = threadIdx.x; i < N; i += 256) { double x = p[i]; s += x; s2 += x*x; }
  __shared__ double sh1[256], sh2[256];
  sh1[threadIdx.x] = s; sh2[threadIdx.x] = s2;
  __syncthreads();
  for (int off = 128; off; off >>= 1) {
    if (threadIdx.x < off) { sh1[threadIdx.x] += sh1[threadIdx.x+off]; sh2[threadIdx.x] += sh2[threadIdx.x+off]; }
    __syncthreads();
  }
  if (threadIdx.x == 0) {
    const double mean = sh1[0]/N;
    const double var  = sh2[0]/N - mean*mean;
    const float rstd = rsqrtf((float)var + EPS_);
    const float sc = gamma[f]*rstd;
    scale[j*F_+f] = sc;
    shift[j*F_+f] = beta[f] - (float)mean*sc;
  }
}

// ---------------------------------------------------------------- fused scan step: prev-combine + r-GEMM + repack
struct RFrag { bf16x8 h[4], lo[4]; };

__device__ __forceinline__ void r_loadq(RFrag& f, int q,
    const u16* __restrict__ Ah, const u16* __restrict__ Al,
    int b0, int lr, int g)
{
  #pragma unroll
  for (int nt = 0; nt < 4; ++nt) {
    const size_t o = ((size_t)q*B_ + (b0 + nt*16 + lr))*32 + g*8;
    f.h[nt]  = *(const bf16x8*)(Ah + o);
    f.lo[nt] = *(const bf16x8*)(Al + o);
  }
}

__global__ __launch_bounds__(256) void r_step(
    const u16* __restrict__ RWh, const u16* __restrict__ RWl,
    const u16* __restrict__ Ain_h, const u16* __restrict__ Ain_l,
    const float* __restrict__ Rb, const float* __restrict__ XwT,
    const float* __restrict__ Xb, const float* __restrict__ HTt,
    const float4* __restrict__ pm4, const float* __restrict__ rPrev,
    const float* __restrict__ Yw, const float* __restrict__ YbF,
    const int* __restrict__ tgt_prev, float* __restrict__ loss_prev,
    int* __restrict__ corr_prev, int have_prev,
    float* __restrict__ rn, u16* __restrict__ Ahi, u16* __restrict__ Alo)
{
  const int f0 = blockIdx.x*64;
  const int b0 = blockIdx.y*64;
  const int tid = threadIdx.x;
  const int w = tid >> 6, l = tid & 63;
  const int lr = l & 15, g = l >> 4;

  __shared__ float T[64][65];
  __shared__ int w_sm[64];

  if (have_prev) {
    const int rr = l >> 2;          // 0..15
    const int ql = l & 3;
    const int row = b0 + w*16 + rr;
    float M = -INFINITY, S = 0.f; int ai = 0x7fffffff;
    for (int p = ql; p < NPB_; p += 4) {
      const float4 qq = pm4[(size_t)p*B_ + row];
      const float mm = qq.x, ss = qq.y;
      const int idx = __float_as_int(qq.z);
      if (mm > M) ai = idx;
      else if (mm == M && idx < ai) ai = idx;
      const float M2 = fmaxf(M, mm);
      const float t1 = (M == -INFINITY) ? 0.f : S*__expf(M - M2);
      S = t1 + ss*__expf(mm - M2);
      M = M2;
    }
    const int tb = tgt_prev[row];
    float td = 0.f;
    for (int f2 = ql; f2 < F_; f2 += 4)
      td = fmaf(rPrev[(size_t)f2*B_ + row], Yw[(size_t)tb*F_ + f2], td);
    #pragma unroll
    for (int off = 1; off <= 2; off <<= 1) {
      td += __shfl_xor(td, off);
      const float om = __shfl_xor(M, off);
      const float os = __shfl_xor(S, off);
      const int   oai = __shfl_xor(ai, off);
      if (om > M) ai = oai;
      else if (om == M && oai < ai) ai = oai;
      const float M2 = fmaxf(M, om);
      const float t1 = (M  == -INFINITY) ? 0.f : S *__expf(M  - M2);
      const float t2 = (om == -INFINITY) ? 0.f : os*__expf(om - M2);
      S = t1 + t2;
      M = M2;
    }
    if (ql == 0) {
      if (blockIdx.x == 0) {
        loss_prev[row] = (M + logf(S)) - (td + YbF[tb]);
        corr_prev[row] = (ai == tb) ? 1 : 0;
      }
      w_sm[w*16 + rr] = ai;
    }
  } else {
    if (l < 16) w_sm[w*16 + l] = 0;
  }

  // ---- R-GEMM ----
  f32x4 acc[4] = {};
  RFrag fA, fB;
  r_loadq(fA, 0, Ain_h, Ain_l, b0, lr, g);
  #pragma unroll
  for (int q = 0; q < KQ_; ++q) {
    RFrag& cur = (q & 1) ? fB : fA;
    RFrag& nxt = (q & 1) ? fA : fB;
    if (q + 1 < KQ_) r_loadq(nxt, q + 1, Ain_h, Ain_l, b0, lr, g);
    SB0();
    {
      const size_t aoff = ((size_t)q*256 + (f0 + w*16 + lr))*32 + g*8;
      const bf16x8 ah = *(const bf16x8*)(RWh + aoff);
      const bf16x8 al = *(const bf16x8*)(RWl + aoff);
      #pragma unroll
      for (int nt = 0; nt < 4; ++nt) {
        acc[nt] = __builtin_amdgcn_mfma_f32_16x16x32_bf16(ah, cur.h[nt],  acc[nt], 0, 0, 0);
        acc[nt] = __builtin_amdgcn_mfma_f32_16x16x32_bf16(ah, cur.lo[nt], acc[nt], 0, 0, 0);
        acc[nt] = __builtin_amdgcn_mfma_f32_16x16x32_bf16(al, cur.h[nt],  acc[nt], 0, 0, 0);
      }
    }
    SB0();
  }
  #pragma unroll
  for (int nt = 0; nt < 4; ++nt)
    #pragma unroll
    for (int j = 0; j < 4; ++j)
      T[w*16 + g*4 + j][nt*16 + lr] = acc[nt][j];
  __syncthreads();

  const int ty = tid >> 4, tx = tid & 15;
  int wv[4];
  #pragma unroll
  for (int j = 0; j < 4; ++j) {
    int t_ = w_sm[tx*4 + j];
    wv[j] = (t_ < 0) ? 0 : (t_ >= V_ ? V_-1 : t_);
  }

  #pragma unroll
  for (int i = 0; i < 4; ++i) {
    const int f = f0 + ty*4 + i;
    if (f < F_) {
      const float rb = Rb[f] + Xb[f];
      #pragma unroll
      for (int j = 0; j < 4; ++j) {
        const int b = b0 + tx*4 + j;
        float v = T[ty*4 + i][tx*4 + j] + rb + XwT[(size_t)wv[j]*F_ + f] + HTt[(size_t)f*B_ + b];
        v = leaky_f(v);
        rn[(size_t)f*B_ + b] = v;
        T[ty*4 + i][tx*4 + j] = v;
      }
    } else {
      #pragma unroll
      for (int j = 0; j < 4; ++j) T[ty*4 + i][tx*4 + j] = 0.f;
    }
  }
  __syncthreads();

  const int bcol = tid & 63;
  const int kk0 = (tid >> 6)*8;
  #pragma unroll
  for (int qh = 0; qh < 2; ++qh) {
    const int q = (f0 >> 5) + qh;
    if (q >= KQ_) continue;
    union { u16 u[8]; uint4 v2[1]; } H, L;
    #pragma unroll
    for (int u = 0; u < 8; ++u) {
      const float x = T[qh*32 + kk0 + u][bcol];
      const u16 h = bf16_rne(x);
      H.u[u] = h;
      L.u[u] = bf16_rne(x - bf16_to_f(h));
    }
    const size_t off = ((size_t)q*B_ + b0 + bcol)*32 + kk0;
    *(uint4*)(Ahi + off) = H.v2[0];
    *(uint4*)(Alo + off) = L.v2[0];
  }
}

// ---------------------------------------------------------------- pack Yw -> padded frag planes + YbP (fused)
__global__ void pack_yw(const float* __restrict__ Yw, const float* __restrict__ Yb,
                        u16* __restrict__ Bhi, u16* __restrict__ Blo, float* __restrict__ YbP)
{
  const int q = blockIdx.x;
  const int v = blockIdx.y*256 + threadIdx.x;
  if (v >= VP_) return;
  if (q == 0) YbP[v] = (v < V_) ? Yb[v] : -INFINITY;
  union { u16 u[32]; uint4 w[4]; } H, L;
  #pragma unroll
  for (int kk = 0; kk < 32; ++kk) {
    const int f = q*32 + kk;
    const float x = (f < F_ && v < V_) ? Yw[(size_t)v*F_ + f] : 0.f;
    const u16 h = bf16_rne(x);
    H.u[kk] = h;
    L.u[kk] = bf16_rne(x - bf16_to_f(h));
  }
  uint4* dh = (uint4*)(Bhi + ((size_t)q*VP_ + v)*32);
  uint4* dl = (uint4*)(Blo + ((size_t)q*VP_ + v)*32);
  #pragma unroll
  for (int i = 0; i < 4; ++i) { dh[i] = H.w[i]; dl[i] = L.w[i]; }
}

// ---------------------------------------------------------------- MFMA Y-GEMM v9: 256x128 tile, LDS-shared B
struct AFr { bf16x8 ah[4], al[4]; };

__device__ __forceinline__ void ya_loadq(AFr& f, int q,
    const u16* __restrict__ Ahi, const u16* __restrict__ Alo,
    int b0, int w, int lr, int g)
{
  #pragma unroll
  for (int mt = 0; mt < 4; ++mt) {
    const size_t o = ((size_t)q*B_ + (b0 + w*64 + mt*16 + lr))*32 + g*8;
    f.ah[mt] = *(const bf16x8*)(Ahi + o);
    f.al[mt] = *(const bf16x8*)(Alo + o);
  }
}

__global__ __launch_bounds__(256) void y_mfma(
    const u16* __restrict__ Ahi, const u16* __restrict__ Alo,
    const u16* __restrict__ Bhi, const u16* __restrict__ Blo,
    const float* __restrict__ YbP, float4* __restrict__ pm4)
{
  const int bid = blockIdx.x;
  const int xcd = bid & 7;
  const int i   = bid >> 3;            // 0..79
  const int by  = i & 7;               // 8 b-tiles of 256 rows
  const int pp  = xcd*10 + (i >> 3);   // 128-col pair index
  if (pp >= NPB_) return;
  const int v0 = pp*128;
  const int b0 = by*256;
  const int tid = threadIdx.x;
  const int w  = tid >> 6;
  const int l  = tid & 63;
  const int lr = l & 15;
  const int g  = l >> 4;

  const int col_s = tid & 127;          // 0..127 staging column
  const int ks16  = (tid >> 7)*16;      // 0 or 16

  __shared__ u16 LH[2][128][40];
  __shared__ u16 LL[2][128][40];

  f32x4 acc[4][8] = {};

  AFr fA, fB;
  // prologue: stage B chunk 0 + load A chunk 0
  {
    const size_t bo = ((size_t)(v0 + col_s))*32 + ks16;
    *(uint4*)&LH[0][col_s][ks16]     = *(const uint4*)(Bhi + bo);
    *(uint4*)&LH[0][col_s][ks16 + 8] = *(const uint4*)(Bhi + bo + 8);
    *(uint4*)&LL[0][col_s][ks16]     = *(const uint4*)(Blo + bo);
    *(uint4*)&LL[0][col_s][ks16 + 8] = *(const uint4*)(Blo + bo + 8);
  }
  ya_loadq(fA, 0, Ahi, Alo, b0, w, lr, g);
  __syncthreads();

  #pragma unroll
  for (int q = 0; q < KQ_; ++q) {
    const int buf = q & 1;
    AFr& cur = (q & 1) ? fB : fA;
    AFr& nxt = (q & 1) ? fA : fB;

    uint4 sbh0, sbh1, sbl0, sbl1;
    if (q + 1 < KQ_) {
      const size_t bo = ((size_t)(q+1)*VP_ + (v0 + col_s))*32 + ks16;
      sbh0 = *(const uint4*)(Bhi + bo);
      sbh1 = *(const uint4*)(Bhi + bo + 8);
      sbl0 = *(const uint4*)(Blo + bo);
      sbl1 = *(const uint4*)(Blo + bo + 8);
      ya_loadq(nxt, q + 1, Ahi, Alo, b0, w, lr, g);
    }
    SB0();
    __builtin_amdgcn_s_setprio(1);
    #pragma unroll
    for (int np = 0; np < 4; ++np) {          // nt pairs: caps live B regs
      bf16x8 bh2[2], bl2[2];
      #pragma unroll
      for (int u = 0; u < 2; ++u) {
        const int nt = np*2 + u;
        bh2[u] = *(const bf16x8*)&LH[buf][nt*16 + lr][g*8];
        bl2[u] = *(const bf16x8*)&LL[buf][nt*16 + lr][g*8];
      }
      #pragma unroll
      for (int mt = 0; mt < 4; ++mt)
        #pragma unroll
        for (int u = 0; u < 2; ++u) {
          const int nt = np*2 + u;
          acc[mt][nt] = __builtin_amdgcn_mfma_f32_16x16x32_bf16(cur.ah[mt], bh2[u], acc[mt][nt], 0, 0, 0);
          acc[mt][nt] = __builtin_amdgcn_mfma_f32_16x16x32_bf16(cur.ah[mt], bl2[u], acc[mt][nt], 0, 0, 0);
          acc[mt][nt] = __builtin_amdgcn_mfma_f32_16x16x32_bf16(cur.al[mt], bh2[u], acc[mt][nt], 0, 0, 0);
        }
    }
    __builtin_amdgcn_s_setprio(0);
    SB0();
    if (q + 1 < KQ_) {
      *(uint4*)&LH[buf ^ 1][col_s][ks16]     = sbh0;
      *(uint4*)&LH[buf ^ 1][col_s][ks16 + 8] = sbh1;
      *(uint4*)&LL[buf ^ 1][col_s][ks16]     = sbl0;
      *(uint4*)&LL[buf ^ 1][col_s][ks16 + 8] = sbl1;
    }
    __syncthreads();
  }

  // ---- pass 1: per-row max + argmax over 128 cols (padded cols y = -inf) ----
  float ybv[8];
  #pragma unroll
  for (int nt = 0; nt < 8; ++nt) ybv[nt] = YbP[v0 + nt*16 + lr];

  float m[4][4]; int ai[4][4];
  #pragma unroll
  for (int mt = 0; mt < 4; ++mt)
    #pragma unroll
    for (int j = 0; j < 4; ++j) { m[mt][j] = -INFINITY; ai[mt][j] = 0x7fffffff; }

  #pragma unroll
  for (int nt = 0; nt < 8; ++nt) {
    const int colv = v0 + nt*16 + lr;
    #pragma unroll
    for (int mt = 0; mt < 4; ++mt)
      #pragma unroll
      for (int j = 0; j < 4; ++j) {
        const float y = acc[mt][nt][j] + ybv[nt];
        if (y > m[mt][j]) { m[mt][j] = y; ai[mt][j] = colv; }   // ascending colv -> first occurrence
      }
  }
  #pragma unroll
  for (int off = 1; off <= 8; off <<= 1) {
    #pragma unroll
    for (int mt = 0; mt < 4; ++mt)
      #pragma unroll
      for (int j = 0; j < 4; ++j) {
        const float om = __shfl_xor(m[mt][j], off);
        const int   oai = __shfl_xor(ai[mt][j], off);
        if (om > m[mt][j] || (om == m[mt][j] && oai < ai[mt][j])) { m[mt][j] = om; ai[mt][j] = oai; }
      }
  }

  // ---- pass 2: sum exp(y - rowmax); padded cols exp(-inf) = 0 ----
  float s[4][4] = {};
  #pragma unroll
  for (int nt = 0; nt < 8; ++nt) {
    #pragma unroll
    for (int mt = 0; mt < 4; ++mt)
      #pragma unroll
      for (int j = 0; j < 4; ++j)
        s[mt][j] += __expf(acc[mt][nt][j] + ybv[nt] - m[mt][j]);
  }
  #pragma unroll
  for (int off = 1; off <= 8; off <<= 1) {
    #pragma unroll
    for (int mt = 0; mt < 4; ++mt)
      #pragma unroll
      for (int j = 0; j < 4; ++j)
        s[mt][j] += __shfl_xor(s[mt][j], off);
  }

  if (lr == 0) {
    #pragma unroll
    for (int mt = 0; mt < 4; ++mt)
      #pragma unroll
      for (int j = 0; j < 4; ++j) {
        const int row = b0 + w*64 + mt*16 + g*4 + j;
        pm4[(size_t)pp*B_ + row] = make_float4(m[mt][j], s[mt][j], __int_as_float(ai[mt][j]), 0.f);
      }
  }
}

// ---------------------------------------------------------------- combine partials (final step only)
__global__ void combine2(const float4* __restrict__ pm4,
                         const float* __restrict__ r, const float* __restrict__ Yw,
                         const float* __restrict__ Yb, const int* __restrict__ tgt,
                         int* __restrict__ w, float* __restrict__ loss_row,
                         int* __restrict__ corr_row)
{
  const int b = blockIdx.x*4 + (threadIdx.x >> 6);
  const int lane = threadIdx.x & 63;
  const int tb = tgt[b];

  float td = 0.f;
  #pragma unroll
  for (int it = 0; it < 4; ++it) {
    const int f = lane + it*64;
    if (f < F_) td = fmaf(r[(size_t)f*B_ + b], Yw[(size_t)tb*F_ + f], td);
  }

  float M = -INFINITY, S = 0.f; int ai = 0x7fffffff;
  for (int p = lane; p < NPB_; p += 64) {
    const float4 q = pm4[(size_t)p*B_ + b];
    const float mm = q.x, s = q.y;
    const int idx = __float_as_int(q.z);
    if (mm > M) ai = idx;
    else if (mm == M && idx < ai) ai = idx;
    const float M2 = fmaxf(M, mm);
    const float t1 = (M == -INFINITY) ? 0.f : S*__expf(M - M2);
    S = t1 + s*__expf(mm - M2);
    M = M2;
  }
  #pragma unroll
  for (int off = 1; off <= 32; off <<= 1) {
    td += __shfl_xor(td, off);
    const float om = __shfl_xor(M, off);
    const float os = __shfl_xor(S, off);
    const int   oai = __shfl_xor(ai, off);
    if (om > M) ai = oai;
    else if (om == M && oai < ai) ai = oai;
    const float M2 = fmaxf(M, om);
    const float t1 = (M  == -INFINITY) ? 0.f : S *__expf(M  - M2);
    const float t2 = (om == -INFINITY) ? 0.f : os*__expf(om - M2);
    S = t1 + t2;
    M = M2;
  }
  if (lane == 0) {
    const float logZ = M + logf(S);
    loss_row[b] = logZ - (td + Yb[tb]);
    corr_row[b] = (ai == tb) ? 1 : 0;
    w[b] = ai;
  }
}

// ---------------------------------------------------------------- final deterministic reduce
__global__ void finalize_k(const float* __restrict__ lr, const int* __restrict__ cr,
                           float* __restrict__ out)
{
  __shared__ float sf[256]; __shared__ int si[256];
  float s = 0.f; int c = 0;
  for (int i = threadIdx.x; i < 7*B_; i += 256) { s += lr[i]; c += cr[i]; }
  sf[threadIdx.x] = s; si[threadIdx.x] = c;
  __syncthreads();
  for (int off = 128; off; off >>= 1) {
    if (threadIdx.x < off) { sf[threadIdx.x] += sf[threadIdx.x+off]; si[threadIdx.x] += si[threadIdx.x+off]; }
    __syncthreads();
  }
  if (threadIdx.x == 0) { out[0] = sf[0] / (float)B_; out[1] = (float)si[0]; }
}

// ================================================================ host
extern "C" void kernel_launch(void* const* d_in, const int* in_sizes, int n_in,
                              void* d_out, int out_size, void* d_ws, size_t ws_size,
                              hipStream_t stream)
{
  (void)in_sizes; (void)n_in; (void)out_size; (void)ws_size;
  const int*   text = (const int*)d_in[0];
  const float* emb  = (const float*)d_in[3];
  const float* gamma= (const float*)d_in[4];
  const float* beta = (const float*)d_in[5];
  const float* c1w = (const float*)d_in[6];  const float* c1b = (const float*)d_in[7];
  const float* c2w = (const float*)d_in[8];  const float* c2b = (const float*)d_in[9];
  const float* c3w = (const float*)d_in[10]; const float* c3b = (const float*)d_in[11];
  const float* c4w = (const float*)d_in[12]; const float* c4b = (const float*)d_in[13];
  const float* Mw = (const float*)d_in[14];  const float* Mb = (const float*)d_in[15];
  const float* Uw = (const float*)d_in[16];  const float* Ub = (const float*)d_in[17];
  const float* Rw = (const float*)d_in[18];  const float* Rb = (const float*)d_in[19];
  const float* Hw = (const float*)d_in[20];  const float* Hb = (const float*)d_in[21];
  const float* Xw = (const float*)d_in[22];  const float* Xb = (const float*)d_in[23];
  const float* Yw = (const float*)d_in[24];  const float* Yb = (const float*)d_in[25];

  float* ws = (float*)d_ws;
  size_t off = 0;
  auto alloc = [&](size_t n)->float* { float* p = ws + off; off += (n + 63) & ~(size_t)63; return p; };

  u16* W1h = (u16*)alloc((size_t)10*256*32/2); u16* W1l = (u16*)alloc((size_t)10*256*32/2);
  u16* W2h = (u16*)alloc((size_t)13*256*32/2); u16* W2l = (u16*)alloc((size_t)13*256*32/2);
  u16* W3h = (u16*)alloc((size_t)19*256*32/2); u16* W3l = (u16*)alloc((size_t)19*256*32/2);
  u16* W4h = (u16*)alloc((size_t)19*256*32/2); u16* W4l = (u16*)alloc((size_t)19*256*32/2);
  u16* RWh = (u16*)alloc((size_t)7*256*32/2);  u16* RWl = (u16*)alloc((size_t)7*256*32/2);
  u16* MW1h= (u16*)alloc((size_t)7*256*32/2);  u16* MW1l= (u16*)alloc((size_t)7*256*32/2);
  u16* MW2h= (u16*)alloc((size_t)7*256*32/2);  u16* MW2l= (u16*)alloc((size_t)7*256*32/2);
  u16* UWh = (u16*)alloc((size_t)6*7*256*32/2);u16* UWl = (u16*)alloc((size_t)6*7*256*32/2);
  u16* HWh = (u16*)alloc((size_t)7*256*32/2);  u16* HWl = (u16*)alloc((size_t)7*256*32/2);
  float* S1 = alloc(3*F_); float* Sh1 = alloc(3*F_);
  float* S2 = alloc(3*F_); float* Sh2 = alloc(3*F_);
  float* S3 = alloc(3*F_); float* Sh3 = alloc(3*F_);
  float* YbP = alloc(VP_);
  float* P  = alloc((size_t)NSEG_*E_*TL_*B_);
  float* Q  = alloc((size_t)NSEG_*F_*6*B_);
  float* VEC = alloc((size_t)NSEG_*F_*B_);
  float* rA = alloc((size_t)F_*B_);
  float* rB = alloc((size_t)F_*B_);
  u16* PKh = (u16*)alloc((size_t)13*10240*32/2);
  u16* PKl = (u16*)alloc((size_t)13*10240*32/2);
  int*   wbuf = (int*)alloc(B_);
  float* loss_rows = alloc((size_t)7*B_);
  int*   corr_rows = (int*)alloc((size_t)7*B_);

  float* X0 = P;
  float* Y1 = Q;
  float* Y2 = P;
  float* Y3 = Q;
  float* Uh = Q;
  float* HT = P;

  const size_t HT_FL = (size_t)7*F_*B_;            // 2,867,200 floats
  u16* YWhi = (u16*)(P + HT_FL);
  u16* YWlo = YWhi + (size_t)KQ_*VP_*32;           // 2,265,088 u16 each (VP_=10112)
  u16* A0h  = YWlo + (size_t)KQ_*VP_*32;
  u16* A0l  = A0h + (size_t)KQ_*B_*32;
  u16* A1h  = A0l + (size_t)KQ_*B_*32;
  u16* A1l  = A1h + (size_t)KQ_*B_*32;
  // tail ends at P + 6,049,792 fl <= 6,451,200 OK

  u16* hAh = (u16*)(Q + (size_t)5734400);
  u16* hAl = hAh + (size_t)KQ_*B_*32;
  u16* hBh = hAl + (size_t)KQ_*B_*32;
  u16* hBl = hBh + (size_t)KQ_*B_*32;

  u16* VPh = PKh;  u16* VPl = PKl;
  u16* USh = PKh;  u16* USl = PKl;

  float4* pm4 = (float4*)Q;                        // [NPB_][B_] float4 = 647,168 fl
  float*  XwT = Q + (size_t)2097152;

  const long long FRZ = (long long)KQ_*B_*32;
  const long long WQZ = (long long)KQ_*256*32;

  const dim3 tb_(32,8);

  PWTab tab;
  tab.e[0] = { c1w,      W1h,  W1l,  300, 300, 10 };
  tab.e[1] = { c2w,      W2h,  W2l,  400, 400, 13 };
  tab.e[2] = { c3w,      W3h,  W3l,  600, 600, 19 };
  tab.e[3] = { c4w,      W4h,  W4l,  600, 600, 19 };
  tab.e[4] = { Rw,       RWh,  RWl,  200, 200, 7 };
  tab.e[5] = { Mw,       MW1h, MW1l, 400, 200, 7 };
  tab.e[6] = { Mw + 200, MW2h, MW2l, 400, 200, 7 };
  tab.e[7] = { Hw,       HWh,  HWl,  200, 200, 7 };
  for (int i = 0; i < 6; ++i)
    tab.e[8+i] = { Uw + (size_t)(1+i)*F_*F_, UWh + (size_t)i*WQZ, UWl + (size_t)i*WQZ, 200, 200, 7 };
  hipLaunchKernelGGL(pack_all_w, dim3(19, 14), dim3(256), 0, stream, tab);

  hipLaunchKernelGGL(gather_x0, dim3(B_/256, TL_, NSEG_), dim3(256), 0, stream, text, emb, X0);

  hipLaunchKernelGGL((conv_gemm3<2,7,10,300,false,false>), dim3(192,3), dim3(256), 0, stream,
      W1h, W1l, X0, (long long)E_*TL_*B_, nullptr, nullptr, c1b, Y1, (long long)F_*6*B_, 6);
  hipLaunchKernelGGL(bn_stats, dim3(F_, NSEG_), dim3(256), 0, stream, Y1, 6, gamma, beta, S1, Sh1);
  hipLaunchKernelGGL((conv_gemm3<2,6,13,400,true,false>), dim3(160,3), dim3(256), 0, stream,
      W2h, W2l, Y1, (long long)F_*6*B_, S1, Sh1, c2b, Y2, (long long)F_*5*B_, 5);
  hipLaunchKernelGGL(bn_stats, dim3(F_, NSEG_), dim3(256), 0, stream, Y2, 5, gamma, beta, S2, Sh2);
  hipLaunchKernelGGL((conv_gemm3<3,5,19,600,true,false>), dim3(96,3), dim3(256), 0, stream,
      W3h, W3l, Y2, (long long)F_*5*B_, S2, Sh2, c3b, Y3, (long long)F_*3*B_, 3);
  hipLaunchKernelGGL(bn_stats, dim3(F_, NSEG_), dim3(256), 0, stream, Y3, 3, gamma, beta, S3, Sh3);
  hipLaunchKernelGGL((conv_gemm3<3,3,19,600,true,true>), dim3(32,3), dim3(256), 0, stream,
      W4h, W4l, Y3, (long long)F_*3*B_, S3, Sh3, c4b, VEC, (long long)F_*B_, 1);

  hipLaunchKernelGGL(pack_x, dim3(B_/256, KQ_, NSEG_), dim3(256), 0, stream,
      VEC, (long long)F_*B_, VPh, VPl, FRZ);
  hipMemsetAsync(hAh, 0, (size_t)2*KQ_*B_*32*2, stream);
  u16 *hch = hAh, *hcl = hAl, *hnh = hBh, *hnl = hBl;
  for (int i = 0; i < 3; ++i) {
    hipLaunchKernelGGL((mf_gemm<true,true,false,true>), dim3(4, 32, 1), dim3(256), 0, stream,
        MW1h, MW1l, 0, VPh + (size_t)i*FRZ, VPl + (size_t)i*FRZ, 0,
        MW2h, MW2l, hch, hcl, Mb, 0, nullptr, 0, hnh, hnl);
    u16* t1 = hch; hch = hnh; hnh = t1;
    u16* t2 = hcl; hcl = hnl; hnl = t2;
  }

  hipLaunchKernelGGL((mf_gemm<false,false,true,false>), dim3(4, 32, 6), dim3(256), 0, stream,
      UWh, UWl, WQZ, hch, hcl, 0, nullptr, nullptr, nullptr, nullptr,
      Ub + F_, F_, Uh + (size_t)F_*B_, (long long)F_*B_, nullptr, nullptr);
  hipLaunchKernelGGL(us_pack, dim3(B_/256, KQ_, 7), dim3(256), 0, stream,
      Uh, USh, USl, FRZ);
  hipLaunchKernelGGL((mf_gemm<false,false,true,false>), dim3(4, 32, 7), dim3(256), 0, stream,
      HWh, HWl, 0, USh, USl, FRZ, nullptr, nullptr, nullptr, nullptr,
      Hb, 0, HT, (long long)F_*B_, nullptr, nullptr);

  hipLaunchKernelGGL(transpose_k, dim3(313,7,1), tb_, 0, stream, Xw, XwT, F_, V_);
  hipLaunchKernelGGL(pack_yw, dim3(KQ_, (VP_+255)/256), dim3(256), 0, stream, Yw, Yb, YWhi, YWlo, YbP);
  hipMemsetAsync(A0h, 0, (size_t)2*KQ_*B_*32*2, stream);

  u16 *cin_h = A0h, *cin_l = A0l, *cout_h = A1h, *cout_l = A1l;
  float *rOld = rA, *rNew = rB;
  for (int t = 0; t < 7; ++t) {
    const int* tgt_prev = text + (size_t)(20 + t)*B_;
    float* lp = (t > 0) ? loss_rows + (size_t)(t-1)*B_ : loss_rows;
    int*   cp = (t > 0) ? corr_rows + (size_t)(t-1)*B_ : corr_rows;
    hipLaunchKernelGGL(r_step, dim3(4, 32), dim3(256), 0, stream,
        RWh, RWl, cin_h, cin_l, Rb, XwT, Xb, HT + (size_t)t*F_*B_,
        pm4, rOld, Yw, Yb, tgt_prev, lp, cp, (int)(t > 0),
        rNew, cout_h, cout_l);
    hipLaunchKernelGGL(y_mfma, dim3(NYB), dim3(256), 0, stream,
        cout_h, cout_l, YWhi, YWlo, YbP, pm4);
    float* tr = rOld; rOld = rNew; rNew = tr;
    u16* th = cin_h; cin_h = cout_h; cout_h = th;
    u16* tl = cin_l; cin_l = cout_l; cout_l = tl;
  }
  hipLaunchKernelGGL(combine2, dim3(B_/4), dim3(256), 0, stream,
      pm4, rOld, Yw, Yb, text + (size_t)27*B_, wbuf,
      loss_rows + (size_t)6*B_, corr_rows + (size_t)6*B_);

  hipLaunchKernelGGL(finalize_k, dim3(1), dim3(256), 0, stream, loss_rows, corr_rows, (float*)d_out);
}

// Round 18
// 933.006 us; speedup vs baseline: 1.0344x; 1.0344x over previous
//
#include <hip/hip_runtime.h>
#include <math.h>

#define V_    10000
#define VP_   10048        // padded vocab for guard-free Y-GEMM (157*64)
#define E_    150
#define F_    200
#define TL_   7
#define B_    2048
#define NSEG_ 3
#define EPS_  1e-5f
#define SLOPE_ 0.01f
#define NB64  (B_/64)
#define NVB   157          // ceil(10000/64) v-parts for MFMA Y-GEMM
#define NYB   1280         // 8 xcd * 20 vb-slots * 8 b-tiles (256 rows each)
#define KQ_   7            // K chunks of 32 for F_=200 (padded 224)

typedef unsigned short u16;
typedef __attribute__((ext_vector_type(8))) short bf16x8;
typedef __attribute__((ext_vector_type(4))) float f32x4;

#define SB0() __builtin_amdgcn_sched_barrier(0)

__device__ __forceinline__ float leaky_f(float x){ return x >= 0.f ? x : SLOPE_*x; }
__device__ __forceinline__ u16 bf16_rne(float x){
  unsigned u = __float_as_uint(x);
  unsigned r = (u + 0x7FFFu + ((u>>16)&1u)) >> 16;
  return (u16)r;
}
__device__ __forceinline__ float bf16_to_f(u16 h){ return __uint_as_float(((unsigned)h)<<16); }

// ---------------------------------------------------------------- transpose (XwT only)
__global__ void transpose_k(const float* __restrict__ in, float* __restrict__ out,
                            int R, int C)
{
  __shared__ float tile[32][33];
  const long long bofs = (long long)blockIdx.z * R * C;
  in += bofs; out += bofs;
  const int c0 = blockIdx.x*32, r0 = blockIdx.y*32;
  const int tx = threadIdx.x, ty = threadIdx.y;  // (32,8)
  for (int i = ty; i < 32; i += 8) {
    int r = r0 + i, c = c0 + tx;
    if (r < R && c < C) tile[i][tx] = in[(long long)r*C + c];
  }
  __syncthreads();
  for (int i = ty; i < 32; i += 8) {
    int c = c0 + i, r = r0 + tx;
    if (c < C && r < R) out[(long long)c*R + r] = tile[tx][i];
  }
}

// ---------------------------------------------------------------- embedding gather
__global__ void gather_x0(const int* __restrict__ text, const float* __restrict__ emb,
                          float* __restrict__ X0)
{
  const int b = blockIdx.x*256 + threadIdx.x;
  const int l = blockIdx.y, j = blockIdx.z;
  const int s = j*TL_ + l;
  const int row = text[(long long)s*B_ + b];
  const float* er = emb + (long long)row*E_;
  float* xp = X0 + ((long long)j*E_*TL_ + l)*B_ + b;
  for (int e = 0; e < E_; ++e) xp[(long long)e*TL_*B_] = er[e];
}

// ---------------------------------------------------------------- unified weight pack (one launch)
struct PWEnt { const float* src; u16* dh; u16* dl; int kstride; int keff; int nq; };
struct PWTab { PWEnt e[14]; };

__global__ void pack_all_w(PWTab tab)
{
  const PWEnt E = tab.e[blockIdx.y];
  const int q = blockIdx.x;
  if (q >= E.nq) return;
  const int f = threadIdx.x;        // 256
  union { u16 u[32]; uint4 v[4]; } H, L;
  #pragma unroll
  for (int kk = 0; kk < 32; ++kk) {
    const int k = q*32 + kk;
    const float x = (k < E.keff && f < F_) ? E.src[(size_t)f*E.kstride + k] : 0.f;
    const u16 h = bf16_rne(x);
    H.u[kk] = h;
    L.u[kk] = bf16_rne(x - bf16_to_f(h));
  }
  uint4* dh = (uint4*)(E.dh + ((size_t)q*256 + f)*32);
  uint4* dl = (uint4*)(E.dl + ((size_t)q*256 + f)*32);
  #pragma unroll
  for (int i = 0; i < 4; ++i) { dh[i] = H.v[i]; dl[i] = L.v[i]; }
}

// ---------------------------------------------------------------- pack fp32 [z][F][B] -> frags [z][q][B][32]
__global__ void pack_x(const float* __restrict__ X, long long xZ,
                       u16* __restrict__ Oh, u16* __restrict__ Ol, long long oZ)
{
  const int q = blockIdx.y, z = blockIdx.z;
  const int b = blockIdx.x*256 + threadIdx.x;
  X  += (size_t)z*xZ;
  Oh += (size_t)z*oZ; Ol += (size_t)z*oZ;
  union { u16 u[32]; uint4 v[4]; } H, L;
  #pragma unroll
  for (int kk = 0; kk < 32; ++kk) {
    const int k = q*32 + kk;
    const float x = (k < F_) ? X[(size_t)k*B_ + b] : 0.f;
    const u16 h = bf16_rne(x);
    H.u[kk] = h;
    L.u[kk] = bf16_rne(x - bf16_to_f(h));
  }
  uint4* dh = (uint4*)(Oh + ((size_t)q*B_ + b)*32);
  uint4* dl = (uint4*)(Ol + ((size_t)q*B_ + b)*32);
  #pragma unroll
  for (int i = 0; i < 4; ++i) { dh[i] = H.v[i]; dl[i] = L.v[i]; }
}

// ---------------------------------------------------------------- fused u_steps + frag pack
__global__ void us_pack(const float* __restrict__ Uh,
                        u16* __restrict__ Oh, u16* __restrict__ Ol, long long oZ)
{
  const int q = blockIdx.y, t = blockIdx.z;
  const int b = blockIdx.x*256 + threadIdx.x;
  const int src = (t == 0) ? 6 : t;
  const float* U = Uh + (size_t)src*F_*B_;
  Oh += (size_t)t*oZ; Ol += (size_t)t*oZ;
  union { u16 u[32]; uint4 v[4]; } H, L;
  #pragma unroll
  for (int kk = 0; kk < 32; ++kk) {
    const int k = q*32 + kk;
    float x = 0.f;
    if (k < F_) {
      x = U[(size_t)k*B_ + b];
      if (t < 5) x = leaky_f(x);
    }
    const u16 h = bf16_rne(x);
    H.u[kk] = h;
    L.u[kk] = bf16_rne(x - bf16_to_f(h));
  }
  uint4* dh = (uint4*)(Oh + ((size_t)q*B_ + b)*32);
  uint4* dl = (uint4*)(Ol + ((size_t)q*B_ + b)*32);
  #pragma unroll
  for (int i = 0; i < 4; ++i) { dh[i] = H.v[i]; dl[i] = L.v[i]; }
}

// ================================================================ MFMA fragment helpers
struct MFrag { bf16x8 h1[4], l1[4], h2[4], l2[4]; };

template<bool TWO>
__device__ __forceinline__ void m_loadq(MFrag& f, int q,
    const u16* __restrict__ X1h, const u16* __restrict__ X1l,
    const u16* __restrict__ X2h, const u16* __restrict__ X2l,
    int b0, int lr, int g)
{
  #pragma unroll
  for (int nt = 0; nt < 4; ++nt) {
    const size_t o = ((size_t)q*B_ + (b0 + nt*16 + lr))*32 + g*8;
    f.h1[nt] = *(const bf16x8*)(X1h + o);
    f.l1[nt] = *(const bf16x8*)(X1l + o);
    if (TWO) {
      f.h2[nt] = *(const bf16x8*)(X2h + o);
      f.l2[nt] = *(const bf16x8*)(X2l + o);
    }
  }
}

template<bool TWO>
__device__ __forceinline__ void m_mfma_chunk(const MFrag& f, int q,
    const u16* __restrict__ W1h, const u16* __restrict__ W1l,
    const u16* __restrict__ W2h, const u16* __restrict__ W2l,
    int f0, int w, int lr, int g, f32x4 acc[4])
{
  const size_t aoff = ((size_t)q*256 + (f0 + w*16 + lr))*32 + g*8;
  {
    const bf16x8 ah = *(const bf16x8*)(W1h + aoff);
    const bf16x8 al = *(const bf16x8*)(W1l + aoff);
    #pragma unroll
    for (int nt = 0; nt < 4; ++nt) {
      acc[nt] = __builtin_amdgcn_mfma_f32_16x16x32_bf16(ah, f.h1[nt], acc[nt], 0, 0, 0);
      acc[nt] = __builtin_amdgcn_mfma_f32_16x16x32_bf16(ah, f.l1[nt], acc[nt], 0, 0, 0);
      acc[nt] = __builtin_amdgcn_mfma_f32_16x16x32_bf16(al, f.h1[nt], acc[nt], 0, 0, 0);
    }
  }
  if (TWO) {
    const bf16x8 ah = *(const bf16x8*)(W2h + aoff);
    const bf16x8 al = *(const bf16x8*)(W2l + aoff);
    #pragma unroll
    for (int nt = 0; nt < 4; ++nt) {
      acc[nt] = __builtin_amdgcn_mfma_f32_16x16x32_bf16(ah, f.h2[nt], acc[nt], 0, 0, 0);
      acc[nt] = __builtin_amdgcn_mfma_f32_16x16x32_bf16(ah, f.l2[nt], acc[nt], 0, 0, 0);
      acc[nt] = __builtin_amdgcn_mfma_f32_16x16x32_bf16(al, f.h2[nt], acc[nt], 0, 0, 0);
    }
  }
}

// ---------------------------------------------------------------- generic MFMA GEMM (pipelined)
template<bool TWO, bool LEAKY, bool OUT_F32, bool OUT_PK>
__global__ __launch_bounds__(256) void mf_gemm(
    const u16* __restrict__ W1h, const u16* __restrict__ W1l, long long wZ,
    const u16* __restrict__ X1h, const u16* __restrict__ X1l, long long xZ,
    const u16* __restrict__ W2h, const u16* __restrict__ W2l,
    const u16* __restrict__ X2h, const u16* __restrict__ X2l,
    const float* __restrict__ bias, long long bZ,
    float* __restrict__ Cf, long long cZ,
    u16* __restrict__ Oh, u16* __restrict__ Ol)
{
  const int z = blockIdx.z;
  W1h += (size_t)z*wZ; W1l += (size_t)z*wZ;
  X1h += (size_t)z*xZ; X1l += (size_t)z*xZ;
  const float* bz = bias + (size_t)z*bZ;
  if (OUT_F32) Cf += (size_t)z*cZ;

  const int f0 = blockIdx.x*64;
  const int b0 = blockIdx.y*64;
  const int tid = threadIdx.x;
  const int w = tid >> 6, l = tid & 63;
  const int lr = l & 15, g = l >> 4;

  __shared__ float T[64][65];

  f32x4 acc[4] = {};
  MFrag fA, fB;
  m_loadq<TWO>(fA, 0, X1h, X1l, X2h, X2l, b0, lr, g);
  #pragma unroll
  for (int q = 0; q < KQ_; ++q) {
    MFrag& cur = (q & 1) ? fB : fA;
    MFrag& nxt = (q & 1) ? fA : fB;
    if (q + 1 < KQ_) m_loadq<TWO>(nxt, q + 1, X1h, X1l, X2h, X2l, b0, lr, g);
    SB0();
    m_mfma_chunk<TWO>(cur, q, W1h, W1l, W2h, W2l, f0, w, lr, g, acc);
    SB0();
  }
  #pragma unroll
  for (int nt = 0; nt < 4; ++nt)
    #pragma unroll
    for (int j = 0; j < 4; ++j)
      T[w*16 + g*4 + j][nt*16 + lr] = acc[nt][j];
  __syncthreads();

  const int ty = tid >> 4, tx = tid & 15;
  #pragma unroll
  for (int i = 0; i < 4; ++i) {
    const int f = f0 + ty*4 + i;
    if (f < F_) {
      const float bb = bz[f];
      #pragma unroll
      for (int j = 0; j < 4; ++j) {
        float v = T[ty*4 + i][tx*4 + j] + bb;
        if (LEAKY) v = leaky_f(v);
        if (OUT_F32) Cf[(size_t)f*B_ + b0 + tx*4 + j] = v;
        T[ty*4 + i][tx*4 + j] = v;
      }
    } else {
      #pragma unroll
      for (int j = 0; j < 4; ++j) T[ty*4 + i][tx*4 + j] = 0.f;
    }
  }
  __syncthreads();

  if (OUT_PK) {
    const int bcol = tid & 63;
    const int kk0 = (tid >> 6)*8;
    #pragma unroll
    for (int qh = 0; qh < 2; ++qh) {
      const int q = (f0 >> 5) + qh;
      if (q >= KQ_) continue;
      union { u16 u[8]; uint4 v2[1]; } H, L;
      #pragma unroll
      for (int u = 0; u < 8; ++u) {
        const float x = T[qh*32 + kk0 + u][bcol];
        const u16 h = bf16_rne(x);
        H.u[u] = h;
        L.u[u] = bf16_rne(x - bf16_to_f(h));
      }
      const size_t off = ((size_t)q*B_ + b0 + bcol)*32 + kk0;
      *(uint4*)(Oh + off) = H.v2[0];
      *(uint4*)(Ol + off) = L.v2[0];
    }
  }
}

// ---------------------------------------------------------------- conv GEMM v3: LDS-shared frags, 3-phase pipeline
template<int KW, int LIN, int NQ, int KEFF, bool BN, bool OUT_LEAKY>
__global__ __launch_bounds__(256) void conv_gemm3(
    const u16* __restrict__ Wh, const u16* __restrict__ Wl,
    const float* __restrict__ Y, long long yZ,
    const float* __restrict__ bnS, const float* __restrict__ bnH,
    const float* __restrict__ bias, float* __restrict__ C, long long cZ, int Lout)
{
  const int z = blockIdx.y;
  Y += (size_t)z*yZ; C += (size_t)z*cZ;
  const float* bs_ = BN ? bnS + (size_t)z*F_ : nullptr;
  const float* bh_ = BN ? bnH + (size_t)z*F_ : nullptr;

  const int c0 = blockIdx.x*64;
  const int tid = threadIdx.x;
  const int w  = tid >> 6;
  const int l  = tid & 63;
  const int lr = l & 15, g = l >> 4;

  const int col_s = tid & 63;
  const int ks    = (tid >> 6)*8;
  const int cg    = c0 + col_s;
  const int ts    = cg >> 11, bcol_s = cg & 2047;

  __shared__ u16 LH[2][64][32];
  __shared__ u16 LL[2][64][32];

  f32x4 acc[4][4] = {};
  float rawA[8], rawB[8];

  {
    const int kb = ks;
    int e = kb / KW, kw = kb - e*KW;
    #pragma unroll
    for (int u = 0; u < 8; ++u) {
      rawA[u] = ((kb + u) < KEFF) ? Y[((size_t)(e*LIN + ts + kw))*B_ + bcol_s] : 0.f;
      ++kw; if (kw == KW) { kw = 0; ++e; }
    }
    union { u16 u[8]; uint4 v; } Hh, Ll;
    e = kb / KW; kw = kb - e*KW;
    #pragma unroll
    for (int u = 0; u < 8; ++u) {
      float x = rawA[u];
      if (BN && (kb + u) < KEFF) x = leaky_f(fmaf(x, bs_[e], bh_[e]));
      const u16 h = bf16_rne(x);
      Hh.u[u] = h; Ll.u[u] = bf16_rne(x - bf16_to_f(h));
      ++kw; if (kw == KW) { kw = 0; ++e; }
    }
    *(uint4*)&LH[0][col_s][ks] = Hh.v;
    *(uint4*)&LL[0][col_s][ks] = Ll.v;
  }
  __syncthreads();

  #pragma unroll
  for (int q = 0; q < NQ; ++q) {
    const int buf = q & 1;
    float (&rw)[8] = (q & 1) ? rawA : rawB;

    if (q + 1 < NQ) {
      const int kb = (q + 1)*32 + ks;
      int e = kb / KW, kw = kb - e*KW;
      #pragma unroll
      for (int u = 0; u < 8; ++u) {
        rw[u] = ((kb + u) < KEFF) ? Y[((size_t)(e*LIN + ts + kw))*B_ + bcol_s] : 0.f;
        ++kw; if (kw == KW) { kw = 0; ++e; }
      }
    }
    SB0();
    {
      bf16x8 bh4[4], bl4[4];
      #pragma unroll
      for (int nt = 0; nt < 4; ++nt) {
        bh4[nt] = *(const bf16x8*)&LH[buf][nt*16 + lr][g*8];
        bl4[nt] = *(const bf16x8*)&LL[buf][nt*16 + lr][g*8];
      }
      bf16x8 ah[4], al[4];
      #pragma unroll
      for (int mt = 0; mt < 4; ++mt) {
        const size_t woff = ((size_t)q*256 + (w*64 + mt*16 + lr))*32 + g*8;
        ah[mt] = *(const bf16x8*)(Wh + woff);
        al[mt] = *(const bf16x8*)(Wl + woff);
      }
      #pragma unroll
      for (int mt = 0; mt < 4; ++mt)
        #pragma unroll
        for (int nt = 0; nt < 4; ++nt) {
          acc[mt][nt] = __builtin_amdgcn_mfma_f32_16x16x32_bf16(ah[mt], bh4[nt], acc[mt][nt], 0, 0, 0);
          acc[mt][nt] = __builtin_amdgcn_mfma_f32_16x16x32_bf16(ah[mt], bl4[nt], acc[mt][nt], 0, 0, 0);
          acc[mt][nt] = __builtin_amdgcn_mfma_f32_16x16x32_bf16(al[mt], bh4[nt], acc[mt][nt], 0, 0, 0);
        }
    }
    SB0();
    if (q + 1 < NQ) {
      const int kb = (q + 1)*32 + ks;
      int e = kb / KW, kw = kb - e*KW;
      union { u16 u[8]; uint4 v; } Hh, Ll;
      #pragma unroll
      for (int u = 0; u < 8; ++u) {
        float x = rw[u];
        if (BN && (kb + u) < KEFF) x = leaky_f(fmaf(x, bs_[e], bh_[e]));
        const u16 h = bf16_rne(x);
        Hh.u[u] = h; Ll.u[u] = bf16_rne(x - bf16_to_f(h));
        ++kw; if (kw == KW) { kw = 0; ++e; }
      }
      *(uint4*)&LH[buf ^ 1][col_s][ks] = Hh.v;
      *(uint4*)&LL[buf ^ 1][col_s][ks] = Ll.v;
    }
    __syncthreads();
  }

  #pragma unroll
  for (int mt = 0; mt < 4; ++mt)
    #pragma unroll
    for (int j = 0; j < 4; ++j) {
      const int f = w*64 + mt*16 + g*4 + j;
      if (f < F_) {
        const float bs = bias[f];
        #pragma unroll
        for (int nt = 0; nt < 4; ++nt) {
          const int col = c0 + nt*16 + lr;
          const int t = col >> 11, b = col & 2047;
          float v = acc[mt][nt][j] + bs;
          if (OUT_LEAKY) v = leaky_f(v);
          C[((size_t)f*Lout + t)*B_ + b] = v;
        }
      }
    }
}

// ---------------------------------------------------------------- BN stats
__global__ void bn_stats(const float* __restrict__ Y, int L,
                         const float* __restrict__ gamma, const float* __restrict__ beta,
                         float* __restrict__ scale, float* __restrict__ shift)
{
  const int f = blockIdx.x, j = blockIdx.y;
  const float* p = Y + ((long long)(j*F_ + f))*L*B_;
  const int N = L*B_;
  double s = 0.0, s2 = 0.0;
  for (int i = threadIdx.x; i < N; i += 256) { double x = p[i]; s += x; s2 += x*x; }
  __shared__ double sh1[256], sh2[256];
  sh1[threadIdx.x] = s; sh2[threadIdx.x] = s2;
  __syncthreads();
  for (int off = 128; off; off >>= 1) {
    if (threadIdx.x < off) { sh1[threadIdx.x] += sh1[threadIdx.x+off]; sh2[threadIdx.x] += sh2[threadIdx.x+off]; }
    __syncthreads();
  }
  if (threadIdx.x == 0) {
    const double mean = sh1[0]/N;
    const double var  = sh2[0]/N - mean*mean;
    const float rstd = rsqrtf((float)var + EPS_);
    const float sc = gamma[f]*rstd;
    scale[j*F_+f] = sc;
    shift[j*F_+f] = beta[f] - (float)mean*sc;
  }
}

// ---------------------------------------------------------------- fused scan step: prev-combine + r-GEMM + repack
struct RFrag { bf16x8 h[4], lo[4]; };

__device__ __forceinline__ void r_loadq(RFrag& f, int q,
    const u16* __restrict__ Ah, const u16* __restrict__ Al,
    int b0, int lr, int g)
{
  #pragma unroll
  for (int nt = 0; nt < 4; ++nt) {
    const size_t o = ((size_t)q*B_ + (b0 + nt*16 + lr))*32 + g*8;
    f.h[nt]  = *(const bf16x8*)(Ah + o);
    f.lo[nt] = *(const bf16x8*)(Al + o);
  }
}

__global__ __launch_bounds__(256) void r_step(
    const u16* __restrict__ RWh, const u16* __restrict__ RWl,
    const u16* __restrict__ Ain_h, const u16* __restrict__ Ain_l,
    const float* __restrict__ Rb, const float* __restrict__ XwT,
    const float* __restrict__ Xb, const float* __restrict__ HTt,
    const float4* __restrict__ pm4, const float* __restrict__ rPrev,
    const float* __restrict__ Yw, const float* __restrict__ YbF,
    const int* __restrict__ tgt_prev, float* __restrict__ loss_prev,
    int* __restrict__ corr_prev, int have_prev,
    float* __restrict__ rn, u16* __restrict__ Ahi, u16* __restrict__ Alo)
{
  const int f0 = blockIdx.x*64;
  const int b0 = blockIdx.y*64;
  const int tid = threadIdx.x;
  const int w = tid >> 6, l = tid & 63;
  const int lr = l & 15, g = l >> 4;

  __shared__ float T[64][65];
  __shared__ int w_sm[64];

  if (have_prev) {
    const int rr = l >> 2;          // 0..15
    const int ql = l & 3;
    const int row = b0 + w*16 + rr;
    float M = -INFINITY, S = 0.f; int ai = 0x7fffffff;
    for (int p = ql; p < NVB; p += 4) {
      const float4 qq = pm4[(size_t)p*B_ + row];
      const float mm = qq.x, ss = qq.y;
      const int idx = __float_as_int(qq.z);
      if (mm > M) ai = idx;
      else if (mm == M && idx < ai) ai = idx;
      const float M2 = fmaxf(M, mm);
      const float t1 = (M == -INFINITY) ? 0.f : S*__expf(M - M2);
      S = t1 + ss*__expf(mm - M2);
      M = M2;
    }
    const int tb = tgt_prev[row];
    float td = 0.f;
    for (int f2 = ql; f2 < F_; f2 += 4)
      td = fmaf(rPrev[(size_t)f2*B_ + row], Yw[(size_t)tb*F_ + f2], td);
    #pragma unroll
    for (int off = 1; off <= 2; off <<= 1) {
      td += __shfl_xor(td, off);
      const float om = __shfl_xor(M, off);
      const float os = __shfl_xor(S, off);
      const int   oai = __shfl_xor(ai, off);
      if (om > M) ai = oai;
      else if (om == M && oai < ai) ai = oai;
      const float M2 = fmaxf(M, om);
      const float t1 = (M  == -INFINITY) ? 0.f : S *__expf(M  - M2);
      const float t2 = (om == -INFINITY) ? 0.f : os*__expf(om - M2);
      S = t1 + t2;
      M = M2;
    }
    if (ql == 0) {
      if (blockIdx.x == 0) {
        loss_prev[row] = (M + logf(S)) - (td + YbF[tb]);
        corr_prev[row] = (ai == tb) ? 1 : 0;
      }
      w_sm[w*16 + rr] = ai;
    }
  } else {
    if (l < 16) w_sm[w*16 + l] = 0;
  }

  // ---- R-GEMM ----
  f32x4 acc[4] = {};
  RFrag fA, fB;
  r_loadq(fA, 0, Ain_h, Ain_l, b0, lr, g);
  #pragma unroll
  for (int q = 0; q < KQ_; ++q) {
    RFrag& cur = (q & 1) ? fB : fA;
    RFrag& nxt = (q & 1) ? fA : fB;
    if (q + 1 < KQ_) r_loadq(nxt, q + 1, Ain_h, Ain_l, b0, lr, g);
    SB0();
    {
      const size_t aoff = ((size_t)q*256 + (f0 + w*16 + lr))*32 + g*8;
      const bf16x8 ah = *(const bf16x8*)(RWh + aoff);
      const bf16x8 al = *(const bf16x8*)(RWl + aoff);
      #pragma unroll
      for (int nt = 0; nt < 4; ++nt) {
        acc[nt] = __builtin_amdgcn_mfma_f32_16x16x32_bf16(ah, cur.h[nt],  acc[nt], 0, 0, 0);
        acc[nt] = __builtin_amdgcn_mfma_f32_16x16x32_bf16(ah, cur.lo[nt], acc[nt], 0, 0, 0);
        acc[nt] = __builtin_amdgcn_mfma_f32_16x16x32_bf16(al, cur.h[nt],  acc[nt], 0, 0, 0);
      }
    }
    SB0();
  }
  #pragma unroll
  for (int nt = 0; nt < 4; ++nt)
    #pragma unroll
    for (int j = 0; j < 4; ++j)
      T[w*16 + g*4 + j][nt*16 + lr] = acc[nt][j];
  __syncthreads();

  const int ty = tid >> 4, tx = tid & 15;
  int wv[4];
  #pragma unroll
  for (int j = 0; j < 4; ++j) {
    int t_ = w_sm[tx*4 + j];
    wv[j] = (t_ < 0) ? 0 : (t_ >= V_ ? V_-1 : t_);
  }

  #pragma unroll
  for (int i = 0; i < 4; ++i) {
    const int f = f0 + ty*4 + i;
    if (f < F_) {
      const float rb = Rb[f] + Xb[f];
      #pragma unroll
      for (int j = 0; j < 4; ++j) {
        const int b = b0 + tx*4 + j;
        float v = T[ty*4 + i][tx*4 + j] + rb + XwT[(size_t)wv[j]*F_ + f] + HTt[(size_t)f*B_ + b];
        v = leaky_f(v);
        rn[(size_t)f*B_ + b] = v;
        T[ty*4 + i][tx*4 + j] = v;
      }
    } else {
      #pragma unroll
      for (int j = 0; j < 4; ++j) T[ty*4 + i][tx*4 + j] = 0.f;
    }
  }
  __syncthreads();

  const int bcol = tid & 63;
  const int kk0 = (tid >> 6)*8;
  #pragma unroll
  for (int qh = 0; qh < 2; ++qh) {
    const int q = (f0 >> 5) + qh;
    if (q >= KQ_) continue;
    union { u16 u[8]; uint4 v2[1]; } H, L;
    #pragma unroll
    for (int u = 0; u < 8; ++u) {
      const float x = T[qh*32 + kk0 + u][bcol];
      const u16 h = bf16_rne(x);
      H.u[u] = h;
      L.u[u] = bf16_rne(x - bf16_to_f(h));
    }
    const size_t off = ((size_t)q*B_ + b0 + bcol)*32 + kk0;
    *(uint4*)(Ahi + off) = H.v2[0];
    *(uint4*)(Alo + off) = L.v2[0];
  }
}

// ---------------------------------------------------------------- pack Yw -> padded frag planes + YbP (fused)
__global__ void pack_yw(const float* __restrict__ Yw, const float* __restrict__ Yb,
                        u16* __restrict__ Bhi, u16* __restrict__ Blo, float* __restrict__ YbP)
{
  const int q = blockIdx.x;
  const int v = blockIdx.y*256 + threadIdx.x;
  if (v >= VP_) return;
  if (q == 0) YbP[v] = (v < V_) ? Yb[v] : -INFINITY;
  union { u16 u[32]; uint4 w[4]; } H, L;
  #pragma unroll
  for (int kk = 0; kk < 32; ++kk) {
    const int f = q*32 + kk;
    const float x = (f < F_ && v < V_) ? Yw[(size_t)v*F_ + f] : 0.f;
    const u16 h = bf16_rne(x);
    H.u[kk] = h;
    L.u[kk] = bf16_rne(x - bf16_to_f(h));
  }
  uint4* dh = (uint4*)(Bhi + ((size_t)q*VP_ + v)*32);
  uint4* dl = (uint4*)(Blo + ((size_t)q*VP_ + v)*32);
  #pragma unroll
  for (int i = 0; i < 4; ++i) { dh[i] = H.w[i]; dl[i] = L.w[i]; }
}

// ---------------------------------------------------------------- MFMA Y-GEMM v8: LDS-shared B, 3-phase pipeline
struct AFr { bf16x8 ah[4], al[4]; };

__device__ __forceinline__ void ya_loadq(AFr& f, int q,
    const u16* __restrict__ Ahi, const u16* __restrict__ Alo,
    int b0, int w, int lr, int g)
{
  #pragma unroll
  for (int mt = 0; mt < 4; ++mt) {
    const size_t o = ((size_t)q*B_ + (b0 + w*64 + mt*16 + lr))*32 + g*8;
    f.ah[mt] = *(const bf16x8*)(Ahi + o);
    f.al[mt] = *(const bf16x8*)(Alo + o);
  }
}

__global__ __launch_bounds__(256, 2) void y_mfma(
    const u16* __restrict__ Ahi, const u16* __restrict__ Alo,
    const u16* __restrict__ Bhi, const u16* __restrict__ Blo,
    const float* __restrict__ YbP, float4* __restrict__ pm4)
{
  const int bid = blockIdx.x;
  const int xcd = bid & 7;
  const int i   = bid >> 3;            // 0..159
  const int by  = i & 7;               // 8 b-tiles of 256 rows
  const int vb  = xcd*20 + (i >> 3);   // 0..159
  if (vb >= NVB) return;
  const int v0 = vb*64;
  const int b0 = by*256;
  const int tid = threadIdx.x;
  const int w  = tid >> 6;
  const int l  = tid & 63;
  const int lr = l & 15;
  const int g  = l >> 4;

  const int col_s = tid & 63;
  const int ks    = (tid >> 6)*8;

  __shared__ u16 LH[2][64][40];   // padded row (40 u16 = 80B) for conflict-light reads
  __shared__ u16 LL[2][64][40];

  f32x4 acc[4][4] = {};

  AFr fA, fB;
  // prologue: stage B chunk 0 + load A chunk 0
  {
    const size_t bo = ((size_t)(v0 + col_s))*32 + ks;
    *(uint4*)&LH[0][col_s][ks] = *(const uint4*)(Bhi + bo);
    *(uint4*)&LL[0][col_s][ks] = *(const uint4*)(Blo + bo);
  }
  ya_loadq(fA, 0, Ahi, Alo, b0, w, lr, g);
  __syncthreads();

  #pragma unroll
  for (int q = 0; q < KQ_; ++q) {
    const int buf = q & 1;
    AFr& cur = (q & 1) ? fB : fA;
    AFr& nxt = (q & 1) ? fA : fB;

    uint4 sbh, sbl;
    if (q + 1 < KQ_) {
      const size_t bo = ((size_t)(q+1)*VP_ + (v0 + col_s))*32 + ks;
      sbh = *(const uint4*)(Bhi + bo);
      sbl = *(const uint4*)(Blo + bo);
      ya_loadq(nxt, q + 1, Ahi, Alo, b0, w, lr, g);
    }
    SB0();
    {
      bf16x8 bh4[4], bl4[4];
      #pragma unroll
      for (int nt = 0; nt < 4; ++nt) {
        bh4[nt] = *(const bf16x8*)&LH[buf][nt*16 + lr][g*8];
        bl4[nt] = *(const bf16x8*)&LL[buf][nt*16 + lr][g*8];
      }
      __builtin_amdgcn_s_setprio(1);
      #pragma unroll
      for (int mt = 0; mt < 4; ++mt)
        #pragma unroll
        for (int nt = 0; nt < 4; ++nt) {
          acc[mt][nt] = __builtin_amdgcn_mfma_f32_16x16x32_bf16(cur.ah[mt], bh4[nt], acc[mt][nt], 0, 0, 0);
          acc[mt][nt] = __builtin_amdgcn_mfma_f32_16x16x32_bf16(cur.ah[mt], bl4[nt], acc[mt][nt], 0, 0, 0);
          acc[mt][nt] = __builtin_amdgcn_mfma_f32_16x16x32_bf16(cur.al[mt], bh4[nt], acc[mt][nt], 0, 0, 0);
        }
      __builtin_amdgcn_s_setprio(0);
    }
    SB0();
    if (q + 1 < KQ_) {
      *(uint4*)&LH[buf ^ 1][col_s][ks] = sbh;
      *(uint4*)&LL[buf ^ 1][col_s][ks] = sbl;
    }
    __syncthreads();
  }

  // ---- pass 1: per-row max + argmax (padded cols give y = -inf) ----
  float ybv[4];
  #pragma unroll
  for (int nt = 0; nt < 4; ++nt) ybv[nt] = YbP[v0 + nt*16 + lr];

  float m[4][4]; int ai[4][4];
  #pragma unroll
  for (int mt = 0; mt < 4; ++mt)
    #pragma unroll
    for (int j = 0; j < 4; ++j) { m[mt][j] = -INFINITY; ai[mt][j] = 0x7fffffff; }

  #pragma unroll
  for (int nt = 0; nt < 4; ++nt) {
    const int colv = v0 + nt*16 + lr;
    #pragma unroll
    for (int mt = 0; mt < 4; ++mt)
      #pragma unroll
      for (int j = 0; j < 4; ++j) {
        const float y = acc[mt][nt][j] + ybv[nt];
        if (y > m[mt][j]) { m[mt][j] = y; ai[mt][j] = colv; }
      }
  }
  #pragma unroll
  for (int off = 1; off <= 8; off <<= 1) {
    #pragma unroll
    for (int mt = 0; mt < 4; ++mt)
      #pragma unroll
      for (int j = 0; j < 4; ++j) {
        const float om = __shfl_xor(m[mt][j], off);
        const int   oai = __shfl_xor(ai[mt][j], off);
        if (om > m[mt][j] || (om == m[mt][j] && oai < ai[mt][j])) { m[mt][j] = om; ai[mt][j] = oai; }
      }
  }

  // ---- pass 2: sum exp(y - rowmax); padded cols exp(-inf) = 0 ----
  float s[4][4] = {};
  #pragma unroll
  for (int nt = 0; nt < 4; ++nt) {
    #pragma unroll
    for (int mt = 0; mt < 4; ++mt)
      #pragma unroll
      for (int j = 0; j < 4; ++j)
        s[mt][j] += __expf(acc[mt][nt][j] + ybv[nt] - m[mt][j]);
  }
  #pragma unroll
  for (int off = 1; off <= 8; off <<= 1) {
    #pragma unroll
    for (int mt = 0; mt < 4; ++mt)
      #pragma unroll
      for (int j = 0; j < 4; ++j)
        s[mt][j] += __shfl_xor(s[mt][j], off);
  }

  if (lr == 0) {
    #pragma unroll
    for (int mt = 0; mt < 4; ++mt)
      #pragma unroll
      for (int j = 0; j < 4; ++j) {
        const int row = b0 + w*64 + mt*16 + g*4 + j;
        pm4[(size_t)vb*B_ + row] = make_float4(m[mt][j], s[mt][j], __int_as_float(ai[mt][j]), 0.f);
      }
  }
}

// ---------------------------------------------------------------- combine partials (final step only)
__global__ void combine2(const float4* __restrict__ pm4,
                         const float* __restrict__ r, const float* __restrict__ Yw,
                         const float* __restrict__ Yb, const int* __restrict__ tgt,
                         int* __restrict__ w, float* __restrict__ loss_row,
                         int* __restrict__ corr_row)
{
  const int b = blockIdx.x*4 + (threadIdx.x >> 6);
  const int lane = threadIdx.x & 63;
  const int tb = tgt[b];

  float td = 0.f;
  #pragma unroll
  for (int it = 0; it < 4; ++it) {
    const int f = lane + it*64;
    if (f < F_) td = fmaf(r[(size_t)f*B_ + b], Yw[(size_t)tb*F_ + f], td);
  }

  float M = -INFINITY, S = 0.f; int ai = 0x7fffffff;
  for (int p = lane; p < NVB; p += 64) {
    const float4 q = pm4[(size_t)p*B_ + b];
    const float mm = q.x, s = q.y;
    const int idx = __float_as_int(q.z);
    if (mm > M) ai = idx;
    else if (mm == M && idx < ai) ai = idx;
    const float M2 = fmaxf(M, mm);
    const float t1 = (M == -INFINITY) ? 0.f : S*__expf(M - M2);
    S = t1 + s*__expf(mm - M2);
    M = M2;
  }
  #pragma unroll
  for (int off = 1; off <= 32; off <<= 1) {
    td += __shfl_xor(td, off);
    const float om = __shfl_xor(M, off);
    const float os = __shfl_xor(S, off);
    const int   oai = __shfl_xor(ai, off);
    if (om > M) ai = oai;
    else if (om == M && oai < ai) ai = oai;
    const float M2 = fmaxf(M, om);
    const float t1 = (M  == -INFINITY) ? 0.f : S *__expf(M  - M2);
    const float t2 = (om == -INFINITY) ? 0.f : os*__expf(om - M2);
    S = t1 + t2;
    M = M2;
  }
  if (lane == 0) {
    const float logZ = M + logf(S);
    loss_row[b] = logZ - (td + Yb[tb]);
    corr_row[b] = (ai == tb) ? 1 : 0;
    w[b] = ai;
  }
}

// ---------------------------------------------------------------- final deterministic reduce
__global__ void finalize_k(const float* __restrict__ lr, const int* __restrict__ cr,
                           float* __restrict__ out)
{
  __shared__ float sf[256]; __shared__ int si[256];
  float s = 0.f; int c = 0;
  for (int i = threadIdx.x; i < 7*B_; i += 256) { s += lr[i]; c += cr[i]; }
  sf[threadIdx.x] = s; si[threadIdx.x] = c;
  __syncthreads();
  for (int off = 128; off; off >>= 1) {
    if (threadIdx.x < off) { sf[threadIdx.x] += sf[threadIdx.x+off]; si[threadIdx.x] += si[threadIdx.x+off]; }
    __syncthreads();
  }
  if (threadIdx.x == 0) { out[0] = sf[0] / (float)B_; out[1] = (float)si[0]; }
}

// ================================================================ host
extern "C" void kernel_launch(void* const* d_in, const int* in_sizes, int n_in,
                              void* d_out, int out_size, void* d_ws, size_t ws_size,
                              hipStream_t stream)
{
  (void)in_sizes; (void)n_in; (void)out_size; (void)ws_size;
  const int*   text = (const int*)d_in[0];
  const float* emb  = (const float*)d_in[3];
  const float* gamma= (const float*)d_in[4];
  const float* beta = (const float*)d_in[5];
  const float* c1w = (const float*)d_in[6];  const float* c1b = (const float*)d_in[7];
  const float* c2w = (const float*)d_in[8];  const float* c2b = (const float*)d_in[9];
  const float* c3w = (const float*)d_in[10]; const float* c3b = (const float*)d_in[11];
  const float* c4w = (const float*)d_in[12]; const float* c4b = (const float*)d_in[13];
  const float* Mw = (const float*)d_in[14];  const float* Mb = (const float*)d_in[15];
  const float* Uw = (const float*)d_in[16];  const float* Ub = (const float*)d_in[17];
  const float* Rw = (const float*)d_in[18];  const float* Rb = (const float*)d_in[19];
  const float* Hw = (const float*)d_in[20];  const float* Hb = (const float*)d_in[21];
  const float* Xw = (const float*)d_in[22];  const float* Xb = (const float*)d_in[23];
  const float* Yw = (const float*)d_in[24];  const float* Yb = (const float*)d_in[25];

  float* ws = (float*)d_ws;
  size_t off = 0;
  auto alloc = [&](size_t n)->float* { float* p = ws + off; off += (n + 63) & ~(size_t)63; return p; };

  u16* W1h = (u16*)alloc((size_t)10*256*32/2); u16* W1l = (u16*)alloc((size_t)10*256*32/2);
  u16* W2h = (u16*)alloc((size_t)13*256*32/2); u16* W2l = (u16*)alloc((size_t)13*256*32/2);
  u16* W3h = (u16*)alloc((size_t)19*256*32/2); u16* W3l = (u16*)alloc((size_t)19*256*32/2);
  u16* W4h = (u16*)alloc((size_t)19*256*32/2); u16* W4l = (u16*)alloc((size_t)19*256*32/2);
  u16* RWh = (u16*)alloc((size_t)7*256*32/2);  u16* RWl = (u16*)alloc((size_t)7*256*32/2);
  u16* MW1h= (u16*)alloc((size_t)7*256*32/2);  u16* MW1l= (u16*)alloc((size_t)7*256*32/2);
  u16* MW2h= (u16*)alloc((size_t)7*256*32/2);  u16* MW2l= (u16*)alloc((size_t)7*256*32/2);
  u16* UWh = (u16*)alloc((size_t)6*7*256*32/2);u16* UWl = (u16*)alloc((size_t)6*7*256*32/2);
  u16* HWh = (u16*)alloc((size_t)7*256*32/2);  u16* HWl = (u16*)alloc((size_t)7*256*32/2);
  float* S1 = alloc(3*F_); float* Sh1 = alloc(3*F_);
  float* S2 = alloc(3*F_); float* Sh2 = alloc(3*F_);
  float* S3 = alloc(3*F_); float* Sh3 = alloc(3*F_);
  float* YbP = alloc(VP_);
  float* P  = alloc((size_t)NSEG_*E_*TL_*B_);
  float* Q  = alloc((size_t)NSEG_*F_*6*B_);
  float* VEC = alloc((size_t)NSEG_*F_*B_);
  float* rA = alloc((size_t)F_*B_);
  float* rB = alloc((size_t)F_*B_);
  u16* PKh = (u16*)alloc((size_t)13*10240*32/2);
  u16* PKl = (u16*)alloc((size_t)13*10240*32/2);
  int*   wbuf = (int*)alloc(B_);
  float* loss_rows = alloc((size_t)7*B_);
  int*   corr_rows = (int*)alloc((size_t)7*B_);

  float* X0 = P;
  float* Y1 = Q;
  float* Y2 = P;
  float* Y3 = Q;
  float* Uh = Q;
  float* HT = P;

  const size_t HT_FL = (size_t)7*F_*B_;
  u16* YWhi = (u16*)(P + HT_FL);
  u16* YWlo = YWhi + (size_t)KQ_*VP_*32;
  u16* A0h  = YWlo + (size_t)KQ_*VP_*32;
  u16* A0l  = A0h + (size_t)KQ_*B_*32;
  u16* A1h  = A0l + (size_t)KQ_*B_*32;
  u16* A1l  = A1h + (size_t)KQ_*B_*32;

  u16* hAh = (u16*)(Q + (size_t)5734400);
  u16* hAl = hAh + (size_t)KQ_*B_*32;
  u16* hBh = hAl + (size_t)KQ_*B_*32;
  u16* hBl = hBh + (size_t)KQ_*B_*32;

  u16* VPh = PKh;  u16* VPl = PKl;
  u16* USh = PKh;  u16* USl = PKl;

  float4* pm4 = (float4*)Q;
  float*  XwT = Q + (size_t)2097152;

  const long long FRZ = (long long)KQ_*B_*32;
  const long long WQZ = (long long)KQ_*256*32;

  const dim3 tb_(32,8);

  PWTab tab;
  tab.e[0] = { c1w,      W1h,  W1l,  300, 300, 10 };
  tab.e[1] = { c2w,      W2h,  W2l,  400, 400, 13 };
  tab.e[2] = { c3w,      W3h,  W3l,  600, 600, 19 };
  tab.e[3] = { c4w,      W4h,  W4l,  600, 600, 19 };
  tab.e[4] = { Rw,       RWh,  RWl,  200, 200, 7 };
  tab.e[5] = { Mw,       MW1h, MW1l, 400, 200, 7 };
  tab.e[6] = { Mw + 200, MW2h, MW2l, 400, 200, 7 };
  tab.e[7] = { Hw,       HWh,  HWl,  200, 200, 7 };
  for (int i = 0; i < 6; ++i)
    tab.e[8+i] = { Uw + (size_t)(1+i)*F_*F_, UWh + (size_t)i*WQZ, UWl + (size_t)i*WQZ, 200, 200, 7 };
  hipLaunchKernelGGL(pack_all_w, dim3(19, 14), dim3(256), 0, stream, tab);

  hipLaunchKernelGGL(gather_x0, dim3(B_/256, TL_, NSEG_), dim3(256), 0, stream, text, emb, X0);

  hipLaunchKernelGGL((conv_gemm3<2,7,10,300,false,false>), dim3(192,3), dim3(256), 0, stream,
      W1h, W1l, X0, (long long)E_*TL_*B_, nullptr, nullptr, c1b, Y1, (long long)F_*6*B_, 6);
  hipLaunchKernelGGL(bn_stats, dim3(F_, NSEG_), dim3(256), 0, stream, Y1, 6, gamma, beta, S1, Sh1);
  hipLaunchKernelGGL((conv_gemm3<2,6,13,400,true,false>), dim3(160,3), dim3(256), 0, stream,
      W2h, W2l, Y1, (long long)F_*6*B_, S1, Sh1, c2b, Y2, (long long)F_*5*B_, 5);
  hipLaunchKernelGGL(bn_stats, dim3(F_, NSEG_), dim3(256), 0, stream, Y2, 5, gamma, beta, S2, Sh2);
  hipLaunchKernelGGL((conv_gemm3<3,5,19,600,true,false>), dim3(96,3), dim3(256), 0, stream,
      W3h, W3l, Y2, (long long)F_*5*B_, S2, Sh2, c3b, Y3, (long long)F_*3*B_, 3);
  hipLaunchKernelGGL(bn_stats, dim3(F_, NSEG_), dim3(256), 0, stream, Y3, 3, gamma, beta, S3, Sh3);
  hipLaunchKernelGGL((conv_gemm3<3,3,19,600,true,true>), dim3(32,3), dim3(256), 0, stream,
      W4h, W4l, Y3, (long long)F_*3*B_, S3, Sh3, c4b, VEC, (long long)F_*B_, 1);

  hipLaunchKernelGGL(pack_x, dim3(B_/256, KQ_, NSEG_), dim3(256), 0, stream,
      VEC, (long long)F_*B_, VPh, VPl, FRZ);
  hipMemsetAsync(hAh, 0, (size_t)2*KQ_*B_*32*2, stream);
  u16 *hch = hAh, *hcl = hAl, *hnh = hBh, *hnl = hBl;
  for (int i = 0; i < 3; ++i) {
    hipLaunchKernelGGL((mf_gemm<true,true,false,true>), dim3(4, 32, 1), dim3(256), 0, stream,
        MW1h, MW1l, 0, VPh + (size_t)i*FRZ, VPl + (size_t)i*FRZ, 0,
        MW2h, MW2l, hch, hcl, Mb, 0, nullptr, 0, hnh, hnl);
    u16* t1 = hch; hch = hnh; hnh = t1;
    u16* t2 = hcl; hcl = hnl; hnl = t2;
  }

  hipLaunchKernelGGL((mf_gemm<false,false,true,false>), dim3(4, 32, 6), dim3(256), 0, stream,
      UWh, UWl, WQZ, hch, hcl, 0, nullptr, nullptr, nullptr, nullptr,
      Ub + F_, F_, Uh + (size_t)F_*B_, (long long)F_*B_, nullptr, nullptr);
  hipLaunchKernelGGL(us_pack, dim3(B_/256, KQ_, 7), dim3(256), 0, stream,
      Uh, USh, USl, FRZ);
  hipLaunchKernelGGL((mf_gemm<false,false,true,false>), dim3(4, 32, 7), dim3(256), 0, stream,
      HWh, HWl, 0, USh, USl, FRZ, nullptr, nullptr, nullptr, nullptr,
      Hb, 0, HT, (long long)F_*B_, nullptr, nullptr);

  hipLaunchKernelGGL(transpose_k, dim3(313,7,1), tb_, 0, stream, Xw, XwT, F_, V_);
  hipLaunchKernelGGL(pack_yw, dim3(KQ_, (VP_+255)/256), dim3(256), 0, stream, Yw, Yb, YWhi, YWlo, YbP);
  hipMemsetAsync(A0h, 0, (size_t)2*KQ_*B_*32*2, stream);

  u16 *cin_h = A0h, *cin_l = A0l, *cout_h = A1h, *cout_l = A1l;
  float *rOld = rA, *rNew = rB;
  for (int t = 0; t < 7; ++t) {
    const int* tgt_prev = text + (size_t)(20 + t)*B_;
    float* lp = (t > 0) ? loss_rows + (size_t)(t-1)*B_ : loss_rows;
    int*   cp = (t > 0) ? corr_rows + (size_t)(t-1)*B_ : corr_rows;
    hipLaunchKernelGGL(r_step, dim3(4, 32), dim3(256), 0, stream,
        RWh, RWl, cin_h, cin_l, Rb, XwT, Xb, HT + (size_t)t*F_*B_,
        pm4, rOld, Yw, Yb, tgt_prev, lp, cp, (int)(t > 0),
        rNew, cout_h, cout_l);
    hipLaunchKernelGGL(y_mfma, dim3(NYB), dim3(256), 0, stream,
        cout_h, cout_l, YWhi, YWlo, YbP, pm4);
    float* tr = rOld; rOld = rNew; rNew = tr;
    u16* th = cin_h; cin_h = cout_h; cout_h = th;
    u16* tl = cin_l; cin_l = cout_l; cout_l = tl;
  }
  hipLaunchKernelGGL(combine2, dim3(B_/4), dim3(256), 0, stream,
      pm4, rOld, Yw, Yb, text + (size_t)27*B_, wbuf,
      loss_rows + (size_t)6*B_, corr_rows + (size_t)6*B_);

  hipLaunchKernelGGL(finalize_k, dim3(1), dim3(256), 0, stream, loss_rows, corr_rows, (float*)d_out);
}

// Round 19
// 930.369 us; speedup vs baseline: 1.0373x; 1.0028x over previous
//
#include <hip/hip_runtime.h>
#include <math.h>

#define V_    10000
#define VP_   10048        // padded vocab for guard-free Y-GEMM (157*64)
#define E_    150
#define F_    200
#define TL_   7
#define B_    2048
#define NSEG_ 3
#define EPS_  1e-5f
#define SLOPE_ 0.01f
#define NB64  (B_/64)
#define NVB   157          // ceil(10000/64) v-parts for MFMA Y-GEMM
#define NYB   1280         // 8 xcd * 20 vb-slots * 8 b-tiles (256 rows each)
#define KQ_   7            // K chunks of 32 for F_=200 (padded 224)

typedef unsigned short u16;
typedef __attribute__((ext_vector_type(8))) short bf16x8;
typedef __attribute__((ext_vector_type(4))) float f32x4;

#define SB0() __builtin_amdgcn_sched_barrier(0)

__device__ __forceinline__ float leaky_f(float x){ return x >= 0.f ? x : SLOPE_*x; }
__device__ __forceinline__ u16 bf16_rne(float x){
  unsigned u = __float_as_uint(x);
  unsigned r = (u + 0x7FFFu + ((u>>16)&1u)) >> 16;
  return (u16)r;
}
__device__ __forceinline__ float bf16_to_f(u16 h){ return __uint_as_float(((unsigned)h)<<16); }

// ---------------------------------------------------------------- transpose (XwT only)
__global__ void transpose_k(const float* __restrict__ in, float* __restrict__ out,
                            int R, int C)
{
  __shared__ float tile[32][33];
  const long long bofs = (long long)blockIdx.z * R * C;
  in += bofs; out += bofs;
  const int c0 = blockIdx.x*32, r0 = blockIdx.y*32;
  const int tx = threadIdx.x, ty = threadIdx.y;  // (32,8)
  for (int i = ty; i < 32; i += 8) {
    int r = r0 + i, c = c0 + tx;
    if (r < R && c < C) tile[i][tx] = in[(long long)r*C + c];
  }
  __syncthreads();
  for (int i = ty; i < 32; i += 8) {
    int c = c0 + i, r = r0 + tx;
    if (c < C && r < R) out[(long long)c*R + r] = tile[tx][i];
  }
}

// ---------------------------------------------------------------- embedding gather (float2 reads; rows are 8B-aligned)
__global__ void gather_x0(const int* __restrict__ text, const float* __restrict__ emb,
                          float* __restrict__ X0)
{
  const int b = blockIdx.x*256 + threadIdx.x;
  const int l = blockIdx.y, j = blockIdx.z;
  const int s = j*TL_ + l;
  const int row = text[(long long)s*B_ + b];
  const float* er = emb + (long long)row*E_;
  float* xp = X0 + ((long long)j*E_*TL_ + l)*B_ + b;
  #pragma unroll 5
  for (int e = 0; e < E_; e += 2) {
    const float2 v = *(const float2*)(er + e);
    xp[(size_t)(e+0)*TL_*B_] = v.x;
    xp[(size_t)(e+1)*TL_*B_] = v.y;
  }
}

// ---------------------------------------------------------------- unified weight pack (one launch)
struct PWEnt { const float* src; u16* dh; u16* dl; int kstride; int keff; int nq; };
struct PWTab { PWEnt e[14]; };

__global__ void pack_all_w(PWTab tab)
{
  const PWEnt E = tab.e[blockIdx.y];
  const int q = blockIdx.x;
  if (q >= E.nq) return;
  const int f = threadIdx.x;        // 256
  union { u16 u[32]; uint4 v[4]; } H, L;
  #pragma unroll
  for (int kk = 0; kk < 32; ++kk) {
    const int k = q*32 + kk;
    const float x = (k < E.keff && f < F_) ? E.src[(size_t)f*E.kstride + k] : 0.f;
    const u16 h = bf16_rne(x);
    H.u[kk] = h;
    L.u[kk] = bf16_rne(x - bf16_to_f(h));
  }
  uint4* dh = (uint4*)(E.dh + ((size_t)q*256 + f)*32);
  uint4* dl = (uint4*)(E.dl + ((size_t)q*256 + f)*32);
  #pragma unroll
  for (int i = 0; i < 4; ++i) { dh[i] = H.v[i]; dl[i] = L.v[i]; }
}

// ---------------------------------------------------------------- pack fp32 [z][F][B] -> frags [z][q][B][32]
__global__ void pack_x(const float* __restrict__ X, long long xZ,
                       u16* __restrict__ Oh, u16* __restrict__ Ol, long long oZ)
{
  const int q = blockIdx.y, z = blockIdx.z;
  const int b = blockIdx.x*256 + threadIdx.x;
  X  += (size_t)z*xZ;
  Oh += (size_t)z*oZ; Ol += (size_t)z*oZ;
  union { u16 u[32]; uint4 v[4]; } H, L;
  #pragma unroll
  for (int kk = 0; kk < 32; ++kk) {
    const int k = q*32 + kk;
    const float x = (k < F_) ? X[(size_t)k*B_ + b] : 0.f;
    const u16 h = bf16_rne(x);
    H.u[kk] = h;
    L.u[kk] = bf16_rne(x - bf16_to_f(h));
  }
  uint4* dh = (uint4*)(Oh + ((size_t)q*B_ + b)*32);
  uint4* dl = (uint4*)(Ol + ((size_t)q*B_ + b)*32);
  #pragma unroll
  for (int i = 0; i < 4; ++i) { dh[i] = H.v[i]; dl[i] = L.v[i]; }
}

// ---------------------------------------------------------------- fused u_steps + frag pack
__global__ void us_pack(const float* __restrict__ Uh,
                        u16* __restrict__ Oh, u16* __restrict__ Ol, long long oZ)
{
  const int q = blockIdx.y, t = blockIdx.z;
  const int b = blockIdx.x*256 + threadIdx.x;
  const int src = (t == 0) ? 6 : t;
  const float* U = Uh + (size_t)src*F_*B_;
  Oh += (size_t)t*oZ; Ol += (size_t)t*oZ;
  union { u16 u[32]; uint4 v[4]; } H, L;
  #pragma unroll
  for (int kk = 0; kk < 32; ++kk) {
    const int k = q*32 + kk;
    float x = 0.f;
    if (k < F_) {
      x = U[(size_t)k*B_ + b];
      if (t < 5) x = leaky_f(x);
    }
    const u16 h = bf16_rne(x);
    H.u[kk] = h;
    L.u[kk] = bf16_rne(x - bf16_to_f(h));
  }
  uint4* dh = (uint4*)(Oh + ((size_t)q*B_ + b)*32);
  uint4* dl = (uint4*)(Ol + ((size_t)q*B_ + b)*32);
  #pragma unroll
  for (int i = 0; i < 4; ++i) { dh[i] = H.v[i]; dl[i] = L.v[i]; }
}

// ================================================================ MFMA fragment helpers
struct MFrag { bf16x8 h1[4], l1[4], h2[4], l2[4]; };

template<bool TWO>
__device__ __forceinline__ void m_loadq(MFrag& f, int q,
    const u16* __restrict__ X1h, const u16* __restrict__ X1l,
    const u16* __restrict__ X2h, const u16* __restrict__ X2l,
    int b0, int lr, int g)
{
  #pragma unroll
  for (int nt = 0; nt < 4; ++nt) {
    const size_t o = ((size_t)q*B_ + (b0 + nt*16 + lr))*32 + g*8;
    f.h1[nt] = *(const bf16x8*)(X1h + o);
    f.l1[nt] = *(const bf16x8*)(X1l + o);
    if (TWO) {
      f.h2[nt] = *(const bf16x8*)(X2h + o);
      f.l2[nt] = *(const bf16x8*)(X2l + o);
    }
  }
}

template<bool TWO>
__device__ __forceinline__ void m_mfma_chunk(const MFrag& f, int q,
    const u16* __restrict__ W1h, const u16* __restrict__ W1l,
    const u16* __restrict__ W2h, const u16* __restrict__ W2l,
    int f0, int w, int lr, int g, f32x4 acc[4])
{
  const size_t aoff = ((size_t)q*256 + (f0 + w*16 + lr))*32 + g*8;
  {
    const bf16x8 ah = *(const bf16x8*)(W1h + aoff);
    const bf16x8 al = *(const bf16x8*)(W1l + aoff);
    #pragma unroll
    for (int nt = 0; nt < 4; ++nt) {
      acc[nt] = __builtin_amdgcn_mfma_f32_16x16x32_bf16(ah, f.h1[nt], acc[nt], 0, 0, 0);
      acc[nt] = __builtin_amdgcn_mfma_f32_16x16x32_bf16(ah, f.l1[nt], acc[nt], 0, 0, 0);
      acc[nt] = __builtin_amdgcn_mfma_f32_16x16x32_bf16(al, f.h1[nt], acc[nt], 0, 0, 0);
    }
  }
  if (TWO) {
    const bf16x8 ah = *(const bf16x8*)(W2h + aoff);
    const bf16x8 al = *(const bf16x8*)(W2l + aoff);
    #pragma unroll
    for (int nt = 0; nt < 4; ++nt) {
      acc[nt] = __builtin_amdgcn_mfma_f32_16x16x32_bf16(ah, f.h2[nt], acc[nt], 0, 0, 0);
      acc[nt] = __builtin_amdgcn_mfma_f32_16x16x32_bf16(ah, f.l2[nt], acc[nt], 0, 0, 0);
      acc[nt] = __builtin_amdgcn_mfma_f32_16x16x32_bf16(al, f.h2[nt], acc[nt], 0, 0, 0);
    }
  }
}

// ---------------------------------------------------------------- generic MFMA GEMM (pipelined)
template<bool TWO, bool LEAKY, bool OUT_F32, bool OUT_PK>
__global__ __launch_bounds__(256) void mf_gemm(
    const u16* __restrict__ W1h, const u16* __restrict__ W1l, long long wZ,
    const u16* __restrict__ X1h, const u16* __restrict__ X1l, long long xZ,
    const u16* __restrict__ W2h, const u16* __restrict__ W2l,
    const u16* __restrict__ X2h, const u16* __restrict__ X2l,
    const float* __restrict__ bias, long long bZ,
    float* __restrict__ Cf, long long cZ,
    u16* __restrict__ Oh, u16* __restrict__ Ol)
{
  const int z = blockIdx.z;
  W1h += (size_t)z*wZ; W1l += (size_t)z*wZ;
  X1h += (size_t)z*xZ; X1l += (size_t)z*xZ;
  const float* bz = bias + (size_t)z*bZ;
  if (OUT_F32) Cf += (size_t)z*cZ;

  const int f0 = blockIdx.x*64;
  const int b0 = blockIdx.y*64;
  const int tid = threadIdx.x;
  const int w = tid >> 6, l = tid & 63;
  const int lr = l & 15, g = l >> 4;

  __shared__ float T[64][65];

  f32x4 acc[4] = {};
  MFrag fA, fB;
  m_loadq<TWO>(fA, 0, X1h, X1l, X2h, X2l, b0, lr, g);
  #pragma unroll
  for (int q = 0; q < KQ_; ++q) {
    MFrag& cur = (q & 1) ? fB : fA;
    MFrag& nxt = (q & 1) ? fA : fB;
    if (q + 1 < KQ_) m_loadq<TWO>(nxt, q + 1, X1h, X1l, X2h, X2l, b0, lr, g);
    SB0();
    m_mfma_chunk<TWO>(cur, q, W1h, W1l, W2h, W2l, f0, w, lr, g, acc);
    SB0();
  }
  #pragma unroll
  for (int nt = 0; nt < 4; ++nt)
    #pragma unroll
    for (int j = 0; j < 4; ++j)
      T[w*16 + g*4 + j][nt*16 + lr] = acc[nt][j];
  __syncthreads();

  const int ty = tid >> 4, tx = tid & 15;
  #pragma unroll
  for (int i = 0; i < 4; ++i) {
    const int f = f0 + ty*4 + i;
    if (f < F_) {
      const float bb = bz[f];
      #pragma unroll
      for (int j = 0; j < 4; ++j) {
        float v = T[ty*4 + i][tx*4 + j] + bb;
        if (LEAKY) v = leaky_f(v);
        if (OUT_F32) Cf[(size_t)f*B_ + b0 + tx*4 + j] = v;
        T[ty*4 + i][tx*4 + j] = v;
      }
    } else {
      #pragma unroll
      for (int j = 0; j < 4; ++j) T[ty*4 + i][tx*4 + j] = 0.f;
    }
  }
  __syncthreads();

  if (OUT_PK) {
    const int bcol = tid & 63;
    const int kk0 = (tid >> 6)*8;
    #pragma unroll
    for (int qh = 0; qh < 2; ++qh) {
      const int q = (f0 >> 5) + qh;
      if (q >= KQ_) continue;
      union { u16 u[8]; uint4 v2[1]; } H, L;
      #pragma unroll
      for (int u = 0; u < 8; ++u) {
        const float x = T[qh*32 + kk0 + u][bcol];
        const u16 h = bf16_rne(x);
        H.u[u] = h;
        L.u[u] = bf16_rne(x - bf16_to_f(h));
      }
      const size_t off = ((size_t)q*B_ + b0 + bcol)*32 + kk0;
      *(uint4*)(Oh + off) = H.v2[0];
      *(uint4*)(Ol + off) = L.v2[0];
    }
  }
}

// ---------------------------------------------------------------- conv GEMM v3: LDS-shared frags, 3-phase pipeline
template<int KW, int LIN, int NQ, int KEFF, bool BN, bool OUT_LEAKY>
__global__ __launch_bounds__(256) void conv_gemm3(
    const u16* __restrict__ Wh, const u16* __restrict__ Wl,
    const float* __restrict__ Y, long long yZ,
    const float* __restrict__ bnS, const float* __restrict__ bnH,
    const float* __restrict__ bias, float* __restrict__ C, long long cZ, int Lout)
{
  const int z = blockIdx.y;
  Y += (size_t)z*yZ; C += (size_t)z*cZ;
  const float* bs_ = BN ? bnS + (size_t)z*F_ : nullptr;
  const float* bh_ = BN ? bnH + (size_t)z*F_ : nullptr;

  const int c0 = blockIdx.x*64;
  const int tid = threadIdx.x;
  const int w  = tid >> 6;
  const int l  = tid & 63;
  const int lr = l & 15, g = l >> 4;

  const int col_s = tid & 63;
  const int ks    = (tid >> 6)*8;
  const int cg    = c0 + col_s;
  const int ts    = cg >> 11, bcol_s = cg & 2047;

  __shared__ u16 LH[2][64][32];
  __shared__ u16 LL[2][64][32];

  f32x4 acc[4][4] = {};
  float rawA[8], rawB[8];

  {
    const int kb = ks;
    int e = kb / KW, kw = kb - e*KW;
    #pragma unroll
    for (int u = 0; u < 8; ++u) {
      rawA[u] = ((kb + u) < KEFF) ? Y[((size_t)(e*LIN + ts + kw))*B_ + bcol_s] : 0.f;
      ++kw; if (kw == KW) { kw = 0; ++e; }
    }
    union { u16 u[8]; uint4 v; } Hh, Ll;
    e = kb / KW; kw = kb - e*KW;
    #pragma unroll
    for (int u = 0; u < 8; ++u) {
      float x = rawA[u];
      if (BN && (kb + u) < KEFF) x = leaky_f(fmaf(x, bs_[e], bh_[e]));
      const u16 h = bf16_rne(x);
      Hh.u[u] = h; Ll.u[u] = bf16_rne(x - bf16_to_f(h));
      ++kw; if (kw == KW) { kw = 0; ++e; }
    }
    *(uint4*)&LH[0][col_s][ks] = Hh.v;
    *(uint4*)&LL[0][col_s][ks] = Ll.v;
  }
  __syncthreads();

  #pragma unroll
  for (int q = 0; q < NQ; ++q) {
    const int buf = q & 1;
    float (&rw)[8] = (q & 1) ? rawA : rawB;

    if (q + 1 < NQ) {
      const int kb = (q + 1)*32 + ks;
      int e = kb / KW, kw = kb - e*KW;
      #pragma unroll
      for (int u = 0; u < 8; ++u) {
        rw[u] = ((kb + u) < KEFF) ? Y[((size_t)(e*LIN + ts + kw))*B_ + bcol_s] : 0.f;
        ++kw; if (kw == KW) { kw = 0; ++e; }
      }
    }
    SB0();
    {
      bf16x8 bh4[4], bl4[4];
      #pragma unroll
      for (int nt = 0; nt < 4; ++nt) {
        bh4[nt] = *(const bf16x8*)&LH[buf][nt*16 + lr][g*8];
        bl4[nt] = *(const bf16x8*)&LL[buf][nt*16 + lr][g*8];
      }
      bf16x8 ah[4], al[4];
      #pragma unroll
      for (int mt = 0; mt < 4; ++mt) {
        const size_t woff = ((size_t)q*256 + (w*64 + mt*16 + lr))*32 + g*8;
        ah[mt] = *(const bf16x8*)(Wh + woff);
        al[mt] = *(const bf16x8*)(Wl + woff);
      }
      #pragma unroll
      for (int mt = 0; mt < 4; ++mt)
        #pragma unroll
        for (int nt = 0; nt < 4; ++nt) {
          acc[mt][nt] = __builtin_amdgcn_mfma_f32_16x16x32_bf16(ah[mt], bh4[nt], acc[mt][nt], 0, 0, 0);
          acc[mt][nt] = __builtin_amdgcn_mfma_f32_16x16x32_bf16(ah[mt], bl4[nt], acc[mt][nt], 0, 0, 0);
          acc[mt][nt] = __builtin_amdgcn_mfma_f32_16x16x32_bf16(al[mt], bh4[nt], acc[mt][nt], 0, 0, 0);
        }
    }
    SB0();
    if (q + 1 < NQ) {
      const int kb = (q + 1)*32 + ks;
      int e = kb / KW, kw = kb - e*KW;
      union { u16 u[8]; uint4 v; } Hh, Ll;
      #pragma unroll
      for (int u = 0; u < 8; ++u) {
        float x = rw[u];
        if (BN && (kb + u) < KEFF) x = leaky_f(fmaf(x, bs_[e], bh_[e]));
        const u16 h = bf16_rne(x);
        Hh.u[u] = h; Ll.u[u] = bf16_rne(x - bf16_to_f(h));
        ++kw; if (kw == KW) { kw = 0; ++e; }
      }
      *(uint4*)&LH[buf ^ 1][col_s][ks] = Hh.v;
      *(uint4*)&LL[buf ^ 1][col_s][ks] = Ll.v;
    }
    __syncthreads();
  }

  #pragma unroll
  for (int mt = 0; mt < 4; ++mt)
    #pragma unroll
    for (int j = 0; j < 4; ++j) {
      const int f = w*64 + mt*16 + g*4 + j;
      if (f < F_) {
        const float bs = bias[f];
        #pragma unroll
        for (int nt = 0; nt < 4; ++nt) {
          const int col = c0 + nt*16 + lr;
          const int t = col >> 11, b = col & 2047;
          float v = acc[mt][nt][j] + bs;
          if (OUT_LEAKY) v = leaky_f(v);
          C[((size_t)f*Lout + t)*B_ + b] = v;
        }
      }
    }
}

// ---------------------------------------------------------------- BN stats
__global__ void bn_stats(const float* __restrict__ Y, int L,
                         const float* __restrict__ gamma, const float* __restrict__ beta,
                         float* __restrict__ scale, float* __restrict__ shift)
{
  const int f = blockIdx.x, j = blockIdx.y;
  const float* p = Y + ((long long)(j*F_ + f))*L*B_;
  const int N = L*B_;
  double s = 0.0, s2 = 0.0;
  for (int i = threadIdx.x; i < N; i += 256) { double x = p[i]; s += x; s2 += x*x; }
  __shared__ double sh1[256], sh2[256];
  sh1[threadIdx.x] = s; sh2[threadIdx.x] = s2;
  __syncthreads();
  for (int off = 128; off; off >>= 1) {
    if (threadIdx.x < off) { sh1[threadIdx.x] += sh1[threadIdx.x+off]; sh2[threadIdx.x] += sh2[threadIdx.x+off]; }
    __syncthreads();
  }
  if (threadIdx.x == 0) {
    const double mean = sh1[0]/N;
    const double var  = sh2[0]/N - mean*mean;
    const float rstd = rsqrtf((float)var + EPS_);
    const float sc = gamma[f]*rstd;
    scale[j*F_+f] = sc;
    shift[j*F_+f] = beta[f] - (float)mean*sc;
  }
}

// ---------------------------------------------------------------- fused scan step: prev-combine + r-GEMM + repack
struct RFrag { bf16x8 h[4], lo[4]; };

__device__ __forceinline__ void r_loadq(RFrag& f, int q,
    const u16* __restrict__ Ah, const u16* __restrict__ Al,
    int b0, int lr, int g)
{
  #pragma unroll
  for (int nt = 0; nt < 4; ++nt) {
    const size_t o = ((size_t)q*B_ + (b0 + nt*16 + lr))*32 + g*8;
    f.h[nt]  = *(const bf16x8*)(Ah + o);
    f.lo[nt] = *(const bf16x8*)(Al + o);
  }
}

__global__ __launch_bounds__(256) void r_step(
    const u16* __restrict__ RWh, const u16* __restrict__ RWl,
    const u16* __restrict__ Ain_h, const u16* __restrict__ Ain_l,
    const float* __restrict__ Rb, const float* __restrict__ XwT,
    const float* __restrict__ Xb, const float* __restrict__ HTt,
    const float4* __restrict__ pm4, const float* __restrict__ rPrev,
    const float* __restrict__ Yw, const float* __restrict__ YbF,
    const int* __restrict__ tgt_prev, float* __restrict__ loss_prev,
    int* __restrict__ corr_prev, int have_prev,
    float* __restrict__ rn, u16* __restrict__ Ahi, u16* __restrict__ Alo)
{
  const int f0 = blockIdx.x*64;
  const int b0 = blockIdx.y*64;
  const int tid = threadIdx.x;
  const int w = tid >> 6, l = tid & 63;
  const int lr = l & 15, g = l >> 4;

  __shared__ float T[64][65];
  __shared__ int w_sm[64];

  if (have_prev) {
    const int rr = l >> 2;          // 0..15
    const int ql = l & 3;
    const int row = b0 + w*16 + rr;
    float M = -INFINITY, S = 0.f; int ai = 0x7fffffff;
    for (int p = ql; p < NVB; p += 4) {
      const float4 qq = pm4[(size_t)p*B_ + row];
      const float mm = qq.x, ss = qq.y;
      const int idx = __float_as_int(qq.z);
      if (mm > M) ai = idx;
      else if (mm == M && idx < ai) ai = idx;
      const float M2 = fmaxf(M, mm);
      const float t1 = (M == -INFINITY) ? 0.f : S*__expf(M - M2);
      S = t1 + ss*__expf(mm - M2);
      M = M2;
    }
    const int tb = tgt_prev[row];
    float td = 0.f;
    for (int f2 = ql; f2 < F_; f2 += 4)
      td = fmaf(rPrev[(size_t)f2*B_ + row], Yw[(size_t)tb*F_ + f2], td);
    #pragma unroll
    for (int off = 1; off <= 2; off <<= 1) {
      td += __shfl_xor(td, off);
      const float om = __shfl_xor(M, off);
      const float os = __shfl_xor(S, off);
      const int   oai = __shfl_xor(ai, off);
      if (om > M) ai = oai;
      else if (om == M && oai < ai) ai = oai;
      const float M2 = fmaxf(M, om);
      const float t1 = (M  == -INFINITY) ? 0.f : S *__expf(M  - M2);
      const float t2 = (om == -INFINITY) ? 0.f : os*__expf(om - M2);
      S = t1 + t2;
      M = M2;
    }
    if (ql == 0) {
      if (blockIdx.x == 0) {
        loss_prev[row] = (M + logf(S)) - (td + YbF[tb]);
        corr_prev[row] = (ai == tb) ? 1 : 0;
      }
      w_sm[w*16 + rr] = ai;
    }
  } else {
    if (l < 16) w_sm[w*16 + l] = 0;
  }

  // ---- R-GEMM ----
  f32x4 acc[4] = {};
  RFrag fA, fB;
  r_loadq(fA, 0, Ain_h, Ain_l, b0, lr, g);
  #pragma unroll
  for (int q = 0; q < KQ_; ++q) {
    RFrag& cur = (q & 1) ? fB : fA;
    RFrag& nxt = (q & 1) ? fA : fB;
    if (q + 1 < KQ_) r_loadq(nxt, q + 1, Ain_h, Ain_l, b0, lr, g);
    SB0();
    {
      const size_t aoff = ((size_t)q*256 + (f0 + w*16 + lr))*32 + g*8;
      const bf16x8 ah = *(const bf16x8*)(RWh + aoff);
      const bf16x8 al = *(const bf16x8*)(RWl + aoff);
      #pragma unroll
      for (int nt = 0; nt < 4; ++nt) {
        acc[nt] = __builtin_amdgcn_mfma_f32_16x16x32_bf16(ah, cur.h[nt],  acc[nt], 0, 0, 0);
        acc[nt] = __builtin_amdgcn_mfma_f32_16x16x32_bf16(ah, cur.lo[nt], acc[nt], 0, 0, 0);
        acc[nt] = __builtin_amdgcn_mfma_f32_16x16x32_bf16(al, cur.h[nt],  acc[nt], 0, 0, 0);
      }
    }
    SB0();
  }
  #pragma unroll
  for (int nt = 0; nt < 4; ++nt)
    #pragma unroll
    for (int j = 0; j < 4; ++j)
      T[w*16 + g*4 + j][nt*16 + lr] = acc[nt][j];
  __syncthreads();

  const int ty = tid >> 4, tx = tid & 15;
  int wv[4];
  #pragma unroll
  for (int j = 0; j < 4; ++j) {
    int t_ = w_sm[tx*4 + j];
    wv[j] = (t_ < 0) ? 0 : (t_ >= V_ ? V_-1 : t_);
  }

  #pragma unroll
  for (int i = 0; i < 4; ++i) {
    const int f = f0 + ty*4 + i;
    if (f < F_) {
      const float rb = Rb[f] + Xb[f];
      #pragma unroll
      for (int j = 0; j < 4; ++j) {
        const int b = b0 + tx*4 + j;
        float v = T[ty*4 + i][tx*4 + j] + rb + XwT[(size_t)wv[j]*F_ + f] + HTt[(size_t)f*B_ + b];
        v = leaky_f(v);
        rn[(size_t)f*B_ + b] = v;
        T[ty*4 + i][tx*4 + j] = v;
      }
    } else {
      #pragma unroll
      for (int j = 0; j < 4; ++j) T[ty*4 + i][tx*4 + j] = 0.f;
    }
  }
  __syncthreads();

  const int bcol = tid & 63;
  const int kk0 = (tid >> 6)*8;
  #pragma unroll
  for (int qh = 0; qh < 2; ++qh) {
    const int q = (f0 >> 5) + qh;
    if (q >= KQ_) continue;
    union { u16 u[8]; uint4 v2[1]; } H, L;
    #pragma unroll
    for (int u = 0; u < 8; ++u) {
      const float x = T[qh*32 + kk0 + u][bcol];
      const u16 h = bf16_rne(x);
      H.u[u] = h;
      L.u[u] = bf16_rne(x - bf16_to_f(h));
    }
    const size_t off = ((size_t)q*B_ + b0 + bcol)*32 + kk0;
    *(uint4*)(Ahi + off) = H.v2[0];
    *(uint4*)(Alo + off) = L.v2[0];
  }
}

// ---------------------------------------------------------------- pack Yw -> padded frag planes + YbP (fused)
__global__ void pack_yw(const float* __restrict__ Yw, const float* __restrict__ Yb,
                        u16* __restrict__ Bhi, u16* __restrict__ Blo, float* __restrict__ YbP)
{
  const int q = blockIdx.x;
  const int v = blockIdx.y*256 + threadIdx.x;
  if (v >= VP_) return;
  if (q == 0) YbP[v] = (v < V_) ? Yb[v] : -INFINITY;
  union { u16 u[32]; uint4 w[4]; } H, L;
  #pragma unroll
  for (int kk = 0; kk < 32; ++kk) {
    const int f = q*32 + kk;
    const float x = (f < F_ && v < V_) ? Yw[(size_t)v*F_ + f] : 0.f;
    const u16 h = bf16_rne(x);
    H.u[kk] = h;
    L.u[kk] = bf16_rne(x - bf16_to_f(h));
  }
  uint4* dh = (uint4*)(Bhi + ((size_t)q*VP_ + v)*32);
  uint4* dl = (uint4*)(Blo + ((size_t)q*VP_ + v)*32);
  #pragma unroll
  for (int i = 0; i < 4; ++i) { dh[i] = H.w[i]; dl[i] = L.w[i]; }
}

// ---------------------------------------------------------------- MFMA Y-GEMM v8: LDS-shared B, 3-phase pipeline
struct AFr { bf16x8 ah[4], al[4]; };

__device__ __forceinline__ void ya_loadq(AFr& f, int q,
    const u16* __restrict__ Ahi, const u16* __restrict__ Alo,
    int b0, int w, int lr, int g)
{
  #pragma unroll
  for (int mt = 0; mt < 4; ++mt) {
    const size_t o = ((size_t)q*B_ + (b0 + w*64 + mt*16 + lr))*32 + g*8;
    f.ah[mt] = *(const bf16x8*)(Ahi + o);
    f.al[mt] = *(const bf16x8*)(Alo + o);
  }
}

__global__ __launch_bounds__(256, 2) void y_mfma(
    const u16* __restrict__ Ahi, const u16* __restrict__ Alo,
    const u16* __restrict__ Bhi, const u16* __restrict__ Blo,
    const float* __restrict__ YbP, float4* __restrict__ pm4)
{
  const int bid = blockIdx.x;
  const int xcd = bid & 7;
  const int i   = bid >> 3;            // 0..159
  const int by  = i & 7;               // 8 b-tiles of 256 rows
  const int vb  = xcd*20 + (i >> 3);   // 0..159
  if (vb >= NVB) return;
  const int v0 = vb*64;
  const int b0 = by*256;
  const int tid = threadIdx.x;
  const int w  = tid >> 6;
  const int l  = tid & 63;
  const int lr = l & 15;
  const int g  = l >> 4;

  const int col_s = tid & 63;
  const int ks    = (tid >> 6)*8;

  __shared__ u16 LH[2][64][40];   // padded row (40 u16 = 80B) for conflict-light reads
  __shared__ u16 LL[2][64][40];

  f32x4 acc[4][4] = {};

  AFr fA, fB;
  // prologue: stage B chunk 0 + load A chunk 0
  {
    const size_t bo = ((size_t)(v0 + col_s))*32 + ks;
    *(uint4*)&LH[0][col_s][ks] = *(const uint4*)(Bhi + bo);
    *(uint4*)&LL[0][col_s][ks] = *(const uint4*)(Blo + bo);
  }
  ya_loadq(fA, 0, Ahi, Alo, b0, w, lr, g);
  __syncthreads();

  #pragma unroll
  for (int q = 0; q < KQ_; ++q) {
    const int buf = q & 1;
    AFr& cur = (q & 1) ? fB : fA;
    AFr& nxt = (q & 1) ? fA : fB;

    uint4 sbh, sbl;
    if (q + 1 < KQ_) {
      const size_t bo = ((size_t)(q+1)*VP_ + (v0 + col_s))*32 + ks;
      sbh = *(const uint4*)(Bhi + bo);
      sbl = *(const uint4*)(Blo + bo);
      ya_loadq(nxt, q + 1, Ahi, Alo, b0, w, lr, g);
    }
    SB0();
    {
      bf16x8 bh4[4], bl4[4];
      #pragma unroll
      for (int nt = 0; nt < 4; ++nt) {
        bh4[nt] = *(const bf16x8*)&LH[buf][nt*16 + lr][g*8];
        bl4[nt] = *(const bf16x8*)&LL[buf][nt*16 + lr][g*8];
      }
      __builtin_amdgcn_s_setprio(1);
      #pragma unroll
      for (int mt = 0; mt < 4; ++mt)
        #pragma unroll
        for (int nt = 0; nt < 4; ++nt) {
          acc[mt][nt] = __builtin_amdgcn_mfma_f32_16x16x32_bf16(cur.ah[mt], bh4[nt], acc[mt][nt], 0, 0, 0);
          acc[mt][nt] = __builtin_amdgcn_mfma_f32_16x16x32_bf16(cur.ah[mt], bl4[nt], acc[mt][nt], 0, 0, 0);
          acc[mt][nt] = __builtin_amdgcn_mfma_f32_16x16x32_bf16(cur.al[mt], bh4[nt], acc[mt][nt], 0, 0, 0);
        }
      __builtin_amdgcn_s_setprio(0);
    }
    SB0();
    if (q + 1 < KQ_) {
      *(uint4*)&LH[buf ^ 1][col_s][ks] = sbh;
      *(uint4*)&LL[buf ^ 1][col_s][ks] = sbl;
    }
    __syncthreads();
  }

  // ---- pass 1: per-row max + argmax (padded cols give y = -inf) ----
  float ybv[4];
  #pragma unroll
  for (int nt = 0; nt < 4; ++nt) ybv[nt] = YbP[v0 + nt*16 + lr];

  float m[4][4]; int ai[4][4];
  #pragma unroll
  for (int mt = 0; mt < 4; ++mt)
    #pragma unroll
    for (int j = 0; j < 4; ++j) { m[mt][j] = -INFINITY; ai[mt][j] = 0x7fffffff; }

  #pragma unroll
  for (int nt = 0; nt < 4; ++nt) {
    const int colv = v0 + nt*16 + lr;
    #pragma unroll
    for (int mt = 0; mt < 4; ++mt)
      #pragma unroll
      for (int j = 0; j < 4; ++j) {
        const float y = acc[mt][nt][j] + ybv[nt];
        if (y > m[mt][j]) { m[mt][j] = y; ai[mt][j] = colv; }
      }
  }
  #pragma unroll
  for (int off = 1; off <= 8; off <<= 1) {
    #pragma unroll
    for (int mt = 0; mt < 4; ++mt)
      #pragma unroll
      for (int j = 0; j < 4; ++j) {
        const float om = __shfl_xor(m[mt][j], off);
        const int   oai = __shfl_xor(ai[mt][j], off);
        if (om > m[mt][j] || (om == m[mt][j] && oai < ai[mt][j])) { m[mt][j] = om; ai[mt][j] = oai; }
      }
  }

  // ---- pass 2: sum exp(y - rowmax); padded cols exp(-inf) = 0 ----
  float s[4][4] = {};
  #pragma unroll
  for (int nt = 0; nt < 4; ++nt) {
    #pragma unroll
    for (int mt = 0; mt < 4; ++mt)
      #pragma unroll
      for (int j = 0; j < 4; ++j)
        s[mt][j] += __expf(acc[mt][nt][j] + ybv[nt] - m[mt][j]);
  }
  #pragma unroll
  for (int off = 1; off <= 8; off <<= 1) {
    #pragma unroll
    for (int mt = 0; mt < 4; ++mt)
      #pragma unroll
      for (int j = 0; j < 4; ++j)
        s[mt][j] += __shfl_xor(s[mt][j], off);
  }

  if (lr == 0) {
    #pragma unroll
    for (int mt = 0; mt < 4; ++mt)
      #pragma unroll
      for (int j = 0; j < 4; ++j) {
        const int row = b0 + w*64 + mt*16 + g*4 + j;
        pm4[(size_t)vb*B_ + row] = make_float4(m[mt][j], s[mt][j], __int_as_float(ai[mt][j]), 0.f);
      }
  }
}

// ---------------------------------------------------------------- combine partials (final step only)
__global__ void combine2(const float4* __restrict__ pm4,
                         const float* __restrict__ r, const float* __restrict__ Yw,
                         const float* __restrict__ Yb, const int* __restrict__ tgt,
                         int* __restrict__ w, float* __restrict__ loss_row,
                         int* __restrict__ corr_row)
{
  const int b = blockIdx.x*4 + (threadIdx.x >> 6);
  const int lane = threadIdx.x & 63;
  const int tb = tgt[b];

  float td = 0.f;
  #pragma unroll
  for (int it = 0; it < 4; ++it) {
    const int f = lane + it*64;
    if (f < F_) td = fmaf(r[(size_t)f*B_ + b], Yw[(size_t)tb*F_ + f], td);
  }

  float M = -INFINITY, S = 0.f; int ai = 0x7fffffff;
  for (int p = lane; p < NVB; p += 64) {
    const float4 q = pm4[(size_t)p*B_ + b];
    const float mm = q.x, s = q.y;
    const int idx = __float_as_int(q.z);
    if (mm > M) ai = idx;
    else if (mm == M && idx < ai) ai = idx;
    const float M2 = fmaxf(M, mm);
    const float t1 = (M == -INFINITY) ? 0.f : S*__expf(M - M2);
    S = t1 + s*__expf(mm - M2);
    M = M2;
  }
  #pragma unroll
  for (int off = 1; off <= 32; off <<= 1) {
    td += __shfl_xor(td, off);
    const float om = __shfl_xor(M, off);
    const float os = __shfl_xor(S, off);
    const int   oai = __shfl_xor(ai, off);
    if (om > M) ai = oai;
    else if (om == M && oai < ai) ai = oai;
    const float M2 = fmaxf(M, om);
    const float t1 = (M  == -INFINITY) ? 0.f : S *__expf(M  - M2);
    const float t2 = (om == -INFINITY) ? 0.f : os*__expf(om - M2);
    S = t1 + t2;
    M = M2;
  }
  if (lane == 0) {
    const float logZ = M + logf(S);
    loss_row[b] = logZ - (td + Yb[tb]);
    corr_row[b] = (ai == tb) ? 1 : 0;
    w[b] = ai;
  }
}

// ---------------------------------------------------------------- final deterministic reduce
__global__ void finalize_k(const float* __restrict__ lr, const int* __restrict__ cr,
                           float* __restrict__ out)
{
  __shared__ float sf[256]; __shared__ int si[256];
  float s = 0.f; int c = 0;
  for (int i = threadIdx.x; i < 7*B_; i += 256) { s += lr[i]; c += cr[i]; }
  sf[threadIdx.x] = s; si[threadIdx.x] = c;
  __syncthreads();
  for (int off = 128; off; off >>= 1) {
    if (threadIdx.x < off) { sf[threadIdx.x] += sf[threadIdx.x+off]; si[threadIdx.x] += si[threadIdx.x+off]; }
    __syncthreads();
  }
  if (threadIdx.x == 0) { out[0] = sf[0] / (float)B_; out[1] = (float)si[0]; }
}

// ================================================================ host
extern "C" void kernel_launch(void* const* d_in, const int* in_sizes, int n_in,
                              void* d_out, int out_size, void* d_ws, size_t ws_size,
                              hipStream_t stream)
{
  (void)in_sizes; (void)n_in; (void)out_size; (void)ws_size;
  const int*   text = (const int*)d_in[0];
  const float* emb  = (const float*)d_in[3];
  const float* gamma= (const float*)d_in[4];
  const float* beta = (const float*)d_in[5];
  const float* c1w = (const float*)d_in[6];  const float* c1b = (const float*)d_in[7];
  const float* c2w = (const float*)d_in[8];  const float* c2b = (const float*)d_in[9];
  const float* c3w = (const float*)d_in[10]; const float* c3b = (const float*)d_in[11];
  const float* c4w = (const float*)d_in[12]; const float* c4b = (const float*)d_in[13];
  const float* Mw = (const float*)d_in[14];  const float* Mb = (const float*)d_in[15];
  const float* Uw = (const float*)d_in[16];  const float* Ub = (const float*)d_in[17];
  const float* Rw = (const float*)d_in[18];  const float* Rb = (const float*)d_in[19];
  const float* Hw = (const float*)d_in[20];  const float* Hb = (const float*)d_in[21];
  const float* Xw = (const float*)d_in[22];  const float* Xb = (const float*)d_in[23];
  const float* Yw = (const float*)d_in[24];  const float* Yb = (const float*)d_in[25];

  float* ws = (float*)d_ws;
  size_t off = 0;
  auto alloc = [&](size_t n)->float* { float* p = ws + off; off += (n + 63) & ~(size_t)63; return p; };

  u16* W1h = (u16*)alloc((size_t)10*256*32/2); u16* W1l = (u16*)alloc((size_t)10*256*32/2);
  u16* W2h = (u16*)alloc((size_t)13*256*32/2); u16* W2l = (u16*)alloc((size_t)13*256*32/2);
  u16* W3h = (u16*)alloc((size_t)19*256*32/2); u16* W3l = (u16*)alloc((size_t)19*256*32/2);
  u16* W4h = (u16*)alloc((size_t)19*256*32/2); u16* W4l = (u16*)alloc((size_t)19*256*32/2);
  u16* RWh = (u16*)alloc((size_t)7*256*32/2);  u16* RWl = (u16*)alloc((size_t)7*256*32/2);
  u16* MW1h= (u16*)alloc((size_t)7*256*32/2);  u16* MW1l= (u16*)alloc((size_t)7*256*32/2);
  u16* MW2h= (u16*)alloc((size_t)7*256*32/2);  u16* MW2l= (u16*)alloc((size_t)7*256*32/2);
  u16* UWh = (u16*)alloc((size_t)6*7*256*32/2);u16* UWl = (u16*)alloc((size_t)6*7*256*32/2);
  u16* HWh = (u16*)alloc((size_t)7*256*32/2);  u16* HWl = (u16*)alloc((size_t)7*256*32/2);
  float* S1 = alloc(3*F_); float* Sh1 = alloc(3*F_);
  float* S2 = alloc(3*F_); float* Sh2 = alloc(3*F_);
  float* S3 = alloc(3*F_); float* Sh3 = alloc(3*F_);
  float* YbP = alloc(VP_);
  float* P  = alloc((size_t)NSEG_*E_*TL_*B_);
  float* Q  = alloc((size_t)NSEG_*F_*6*B_);
  float* VEC = alloc((size_t)NSEG_*F_*B_);
  float* rA = alloc((size_t)F_*B_);
  float* rB = alloc((size_t)F_*B_);
  u16* PKh = (u16*)alloc((size_t)13*10240*32/2);
  u16* PKl = (u16*)alloc((size_t)13*10240*32/2);
  int*   wbuf = (int*)alloc(B_);
  float* loss_rows = alloc((size_t)7*B_);
  int*   corr_rows = (int*)alloc((size_t)7*B_);

  float* X0 = P;
  float* Y1 = Q;
  float* Y2 = P;
  float* Y3 = Q;
  float* Uh = Q;
  float* HT = P;

  const size_t HT_FL = (size_t)7*F_*B_;
  u16* YWhi = (u16*)(P + HT_FL);
  u16* YWlo = YWhi + (size_t)KQ_*VP_*32;
  u16* A0h  = YWlo + (size_t)KQ_*VP_*32;
  u16* A0l  = A0h + (size_t)KQ_*B_*32;
  u16* A1h  = A0l + (size_t)KQ_*B_*32;
  u16* A1l  = A1h + (size_t)KQ_*B_*32;

  u16* hAh = (u16*)(Q + (size_t)5734400);
  u16* hAl = hAh + (size_t)KQ_*B_*32;
  u16* hBh = hAl + (size_t)KQ_*B_*32;
  u16* hBl = hBh + (size_t)KQ_*B_*32;

  u16* VPh = PKh;  u16* VPl = PKl;
  u16* USh = PKh;  u16* USl = PKl;

  float4* pm4 = (float4*)Q;
  float*  XwT = Q + (size_t)2097152;

  const long long FRZ = (long long)KQ_*B_*32;
  const long long WQZ = (long long)KQ_*256*32;

  const dim3 tb_(32,8);

  PWTab tab;
  tab.e[0] = { c1w,      W1h,  W1l,  300, 300, 10 };
  tab.e[1] = { c2w,      W2h,  W2l,  400, 400, 13 };
  tab.e[2] = { c3w,      W3h,  W3l,  600, 600, 19 };
  tab.e[3] = { c4w,      W4h,  W4l,  600, 600, 19 };
  tab.e[4] = { Rw,       RWh,  RWl,  200, 200, 7 };
  tab.e[5] = { Mw,       MW1h, MW1l, 400, 200, 7 };
  tab.e[6] = { Mw + 200, MW2h, MW2l, 400, 200, 7 };
  tab.e[7] = { Hw,       HWh,  HWl,  200, 200, 7 };
  for (int i = 0; i < 6; ++i)
    tab.e[8+i] = { Uw + (size_t)(1+i)*F_*F_, UWh + (size_t)i*WQZ, UWl + (size_t)i*WQZ, 200, 200, 7 };
  hipLaunchKernelGGL(pack_all_w, dim3(19, 14), dim3(256), 0, stream, tab);

  hipLaunchKernelGGL(gather_x0, dim3(B_/256, TL_, NSEG_), dim3(256), 0, stream, text, emb, X0);

  hipLaunchKernelGGL((conv_gemm3<2,7,10,300,false,false>), dim3(192,3), dim3(256), 0, stream,
      W1h, W1l, X0, (long long)E_*TL_*B_, nullptr, nullptr, c1b, Y1, (long long)F_*6*B_, 6);
  hipLaunchKernelGGL(bn_stats, dim3(F_, NSEG_), dim3(256), 0, stream, Y1, 6, gamma, beta, S1, Sh1);
  hipLaunchKernelGGL((conv_gemm3<2,6,13,400,true,false>), dim3(160,3), dim3(256), 0, stream,
      W2h, W2l, Y1, (long long)F_*6*B_, S1, Sh1, c2b, Y2, (long long)F_*5*B_, 5);
  hipLaunchKernelGGL(bn_stats, dim3(F_, NSEG_), dim3(256), 0, stream, Y2, 5, gamma, beta, S2, Sh2);
  hipLaunchKernelGGL((conv_gemm3<3,5,19,600,true,false>), dim3(96,3), dim3(256), 0, stream,
      W3h, W3l, Y2, (long long)F_*5*B_, S2, Sh2, c3b, Y3, (long long)F_*3*B_, 3);
  hipLaunchKernelGGL(bn_stats, dim3(F_, NSEG_), dim3(256), 0, stream, Y3, 3, gamma, beta, S3, Sh3);
  hipLaunchKernelGGL((conv_gemm3<3,3,19,600,true,true>), dim3(32,3), dim3(256), 0, stream,
      W4h, W4l, Y3, (long long)F_*3*B_, S3, Sh3, c4b, VEC, (long long)F_*B_, 1);

  hipLaunchKernelGGL(pack_x, dim3(B_/256, KQ_, NSEG_), dim3(256), 0, stream,
      VEC, (long long)F_*B_, VPh, VPl, FRZ);
  hipMemsetAsync(hAh, 0, (size_t)2*KQ_*B_*32*2, stream);
  u16 *hch = hAh, *hcl = hAl, *hnh = hBh, *hnl = hBl;
  for (int i = 0; i < 3; ++i) {
    hipLaunchKernelGGL((mf_gemm<true,true,false,true>), dim3(4, 32, 1), dim3(256), 0, stream,
        MW1h, MW1l, 0, VPh + (size_t)i*FRZ, VPl + (size_t)i*FRZ, 0,
        MW2h, MW2l, hch, hcl, Mb, 0, nullptr, 0, hnh, hnl);
    u16* t1 = hch; hch = hnh; hnh = t1;
    u16* t2 = hcl; hcl = hnl; hnl = t2;
  }

  hipLaunchKernelGGL((mf_gemm<false,false,true,false>), dim3(4, 32, 6), dim3(256), 0, stream,
      UWh, UWl, WQZ, hch, hcl, 0, nullptr, nullptr, nullptr, nullptr,
      Ub + F_, F_, Uh + (size_t)F_*B_, (long long)F_*B_, nullptr, nullptr);
  hipLaunchKernelGGL(us_pack, dim3(B_/256, KQ_, 7), dim3(256), 0, stream,
      Uh, USh, USl, FRZ);
  hipLaunchKernelGGL((mf_gemm<false,false,true,false>), dim3(4, 32, 7), dim3(256), 0, stream,
      HWh, HWl, 0, USh, USl, FRZ, nullptr, nullptr, nullptr, nullptr,
      Hb, 0, HT, (long long)F_*B_, nullptr, nullptr);

  hipLaunchKernelGGL(transpose_k, dim3(313,7,1), tb_, 0, stream, Xw, XwT, F_, V_);
  hipLaunchKernelGGL(pack_yw, dim3(KQ_, (VP_+255)/256), dim3(256), 0, stream, Yw, Yb, YWhi, YWlo, YbP);
  hipMemsetAsync(A0h, 0, (size_t)2*KQ_*B_*32*2, stream);

  u16 *cin_h = A0h, *cin_l = A0l, *cout_h = A1h, *cout_l = A1l;
  float *rOld = rA, *rNew = rB;
  for (int t = 0; t < 7; ++t) {
    const int* tgt_prev = text + (size_t)(20 + t)*B_;
    float* lp = (t > 0) ? loss_rows + (size_t)(t-1)*B_ : loss_rows;
    int*   cp = (t > 0) ? corr_rows + (size_t)(t-1)*B_ : corr_rows;
    hipLaunchKernelGGL(r_step, dim3(4, 32), dim3(256), 0, stream,
        RWh, RWl, cin_h, cin_l, Rb, XwT, Xb, HT + (size_t)t*F_*B_,
        pm4, rOld, Yw, Yb, tgt_prev, lp, cp, (int)(t > 0),
        rNew, cout_h, cout_l);
    hipLaunchKernelGGL(y_mfma, dim3(NYB), dim3(256), 0, stream,
        cout_h, cout_l, YWhi, YWlo, YbP, pm4);
    float* tr = rOld; rOld = rNew; rNew = tr;
    u16* th = cin_h; cin_h = cout_h; cout_h = th;
    u16* tl = cin_l; cin_l = cout_l; cout_l = tl;
  }
  hipLaunchKernelGGL(combine2, dim3(B_/4), dim3(256), 0, stream,
      pm4, rOld, Yw, Yb, text + (size_t)27*B_, wbuf,
      loss_rows + (size_t)6*B_, corr_rows + (size_t)6*B_);

  hipLaunchKernelGGL(finalize_k, dim3(1), dim3(256), 0, stream, loss_rows, corr_rows, (float*)d_out);
}